// Round 8
// baseline (1732.123 us; speedup 1.0000x reference)
//
#include <hip/hip_runtime.h>
#include <math.h>

#define EPS_F 1e-15f
#define NRBF 20
#define CUTOFF_F 5.0f
#define PI_F 3.14159265358979323846f

typedef unsigned short u16;
typedef _Float16 f16;
typedef f16 f16x8 __attribute__((ext_vector_type(8)));
typedef f16 f16x4 __attribute__((ext_vector_type(4)));
typedef f16 f16x2 __attribute__((ext_vector_type(2)));
typedef float floatx4 __attribute__((ext_vector_type(4)));

__device__ __forceinline__ float silu_f(float x) { return x / (1.0f + expf(-x)); }

// ---------------- counting sort: histogram + scan ----------------
__global__ __launch_bounds__(256) void hist_kernel(
    const int* __restrict__ nbr, int* __restrict__ hist, int E)
{
  int e = blockIdx.x * 256 + threadIdx.x;
  if (e >= E) return;
  atomicAdd(hist + nbr[2 * e], 1);
}

// single-block exclusive scan, wave-shfl based (few barriers)
__global__ __launch_bounds__(1024) void scan_kernel(
    const int* __restrict__ hist, int* __restrict__ start,
    int* __restrict__ cursor, int N)
{
  __shared__ int wsum[16];
  __shared__ int carry_s;
  int tid = threadIdx.x;
  int lane = tid & 63, wid = tid >> 6;
  if (tid == 0) carry_s = 0;
  __syncthreads();
  for (int base = 0; base < N; base += 1024) {
    int x = (base + tid < N) ? hist[base + tid] : 0;
    int v = x;
#pragma unroll
    for (int o = 1; o < 64; o <<= 1) {
      int t2 = __shfl_up(v, o, 64);
      if (lane >= o) v += t2;
    }
    if (lane == 63) wsum[wid] = v;
    __syncthreads();
    if (tid < 16) {
      int w = wsum[tid];
#pragma unroll
      for (int o = 1; o < 16; o <<= 1) {
        int t2 = __shfl_up(w, o, 64);
        if (tid >= o) w += t2;
      }
      wsum[tid] = w;
    }
    __syncthreads();
    int wbase = (wid == 0) ? 0 : wsum[wid - 1];
    int incl = v + wbase;
    int carry = carry_s;
    if (base + tid < N) {
      int ex = carry + incl - x;
      start[base + tid] = ex;
      cursor[base + tid] = ex;
    }
    __syncthreads();
    if (tid == 1023) carry_s = carry + incl;
    __syncthreads();
  }
  if (tid == 0) start[N] = carry_s;
}

// ---------------- scatter edge IDs ----------------
__global__ __launch_bounds__(256) void scatter_id_kernel(
    const int* __restrict__ nbr, int* __restrict__ cursor,
    int* __restrict__ order, int E)
{
  int e = blockIdx.x * 256 + threadIdx.x;
  if (e >= E) return;
  int pos = atomicAdd(cursor + nbr[2 * e], 1);
  order[pos] = e;
}

// ---------------- canonicalize: wave rank-sort of each atom's segment ----------------
__global__ __launch_bounds__(256) void segsort_kernel(
    int* __restrict__ order, const int* __restrict__ start, int N)
{
  int wi = blockIdx.x * 4 + (threadIdx.x >> 6);
  int lane = threadIdx.x & 63;
  if (wi >= N) return;
  int s0 = start[wi], s1 = start[wi + 1];
  int len = s1 - s0;
  if (len <= 1) return;
  if (len <= 64) {
    int id = (lane < len) ? order[s0 + lane] : 0x7FFFFFFF;
    int rank = 0;
#pragma unroll
    for (int k = 0; k < 64; ++k) {
      int other = __shfl(id, k, 64);
      rank += (other < id) ? 1 : 0;
    }
    if (lane < len) order[s0 + rank] = id;
  } else if (lane == 0) {
    for (int a = s0 + 1; a < s1; ++a) {
      int key = order[a];
      int b = a - 1;
      while (b >= s0 && order[b] > key) { order[b + 1] = order[b]; --b; }
      order[b + 1] = key;
    }
  }
}

// ---------------- geometry gather-fill (deterministic) ----------------
// rbf_h row layout (32 f16): slots 0..19 = sin(k_n d)/d * env   (env pre-folded)
//                            slot  20    = env
//                            slots 21..31 = 0
__global__ __launch_bounds__(256) void geom_fill_kernel(
    const int* __restrict__ order, const int* __restrict__ nbr,
    const float* __restrict__ xyz, int2* __restrict__ ij_s,
    float* __restrict__ unit_s, f16* __restrict__ rbf_h, int E)
{
  int p = blockIdx.x * 256 + threadIdx.x;
  if (p >= E) return;
  int e = order[p];
  int i = nbr[2 * e], j = nbr[2 * e + 1];
  float dx = xyz[3 * j + 0] - xyz[3 * i + 0];
  float dy = xyz[3 * j + 1] - xyz[3 * i + 1];
  float dz = xyz[3 * j + 2] - xyz[3 * i + 2];
  float d2 = dx * dx + dy * dy + dz * dz + 3.0f * EPS_F;  // ref adds EPS per comp
  float d = sqrtf(d2);
  float inv_d = 1.0f / d;
  ij_s[p] = make_int2(i, j);
  unit_s[3 * p + 0] = dx * inv_d;
  unit_s[3 * p + 1] = dy * inv_d;
  unit_s[3 * p + 2] = dz * inv_d;
  float x = d * (PI_F / CUTOFF_F);
  float s1, c1;
  __sincosf(x, &s1, &c1);
  float envv = (d < CUTOFF_F) ? 0.5f * (c1 + 1.0f) : 0.0f;
  f16 tmp[32];
  float two_c = 2.0f * c1;
  float env_inv_d = envv * inv_d;
  float sp = 0.0f, sn = s1;           // Chebyshev recurrence for sin(n*x)
  tmp[0] = (f16)(sn * env_inv_d);
#pragma unroll
  for (int n = 1; n < NRBF; ++n) {
    float nx = two_c * sn - sp;
    sp = sn; sn = nx;
    tmp[n] = (f16)(sn * env_inv_d);
  }
  tmp[NRBF] = (f16)envv;
#pragma unroll
  for (int n = NRBF + 1; n < 32; ++n) tmp[n] = (f16)0.0f;
#pragma unroll
  for (int g = 0; g < 4; ++g)
    *(f16x8*)(rbf_h + (size_t)p * 32 + g * 8) = *(f16x8*)&tmp[g * 8];
}

// ---------------- pre-pack dwx = [dist_w; dist_b; 0] into MFMA B-fragment order ----------------
__global__ __launch_bounds__(256) void dwfrag_kernel(
    const float* __restrict__ dw, const float* __restrict__ db,
    f16* __restrict__ dwf)
{
  int idx = blockIdx.x * 256 + threadIdx.x;
  if (idx >= 3 * 24 * 64 * 8) return;
  int q = idx & 7;
  int lane = (idx >> 3) & 63;
  int ct = (idx >> 9) % 24;
  int l = idx / (24 * 64 * 8);
  int k = (lane >> 4) * 8 + q;
  int col = ct * 16 + (lane & 15);
  float val = 0.f;
  if (k < NRBF) val = dw[(size_t)l * NRBF * 384 + (size_t)k * 384 + col];
  else if (k == NRBF) val = db[(size_t)l * 384 + col];
  dwf[idx] = (f16)val;
}

// ---------------- s = embed[z] (fp32 + f16 mirror) ----------------
__global__ __launch_bounds__(256) void embed_kernel(
    const int* __restrict__ z, const float* __restrict__ embed,
    float* __restrict__ s, f16* __restrict__ s_h, int N)
{
  int idx = blockIdx.x * 256 + threadIdx.x;
  if (idx >= N * 128) return;
  int n = idx >> 7, f = idx & 127;
  float x = embed[z[n] * 128 + f];
  s[idx] = x;
  s_h[idx] = (f16)x;
}

__global__ __launch_bounds__(256) void w1t_kernel(
    const float* __restrict__ w1, f16* __restrict__ w1t)
{
  int idx = blockIdx.x * 256 + threadIdx.x;
  if (idx >= 64 * 128) return;
  int n = idx >> 7, k = idx & 127;
  w1t[idx] = (f16)w1[(size_t)k * 64 + n];
}

// ---------------- f16 MFMA GEMM ----------------
template <bool SILU, int OUT, bool AH>
__global__ __launch_bounds__(256) void gemm_kernel(
    const void* __restrict__ Ap, const float* __restrict__ W,
    const float* __restrict__ bias, const float* __restrict__ rowscale,
    void* __restrict__ Cout, int M, int N, int K)
{
  __shared__ f16 As[64][40];
  __shared__ f16 Bs[64][40];
  int t = threadIdx.x;
  int wave = t >> 6, lane = t & 63;
  int rw = wave & 1, cw = wave >> 1;
  int lr = lane & 15, quad = lane >> 4;
  int row0 = blockIdx.x * 64, col0 = blockIdx.y * 64;
  floatx4 acc[2][2] = {};
  for (int k0 = 0; k0 < K; k0 += 32) {
    if (AH) {
      const f16* A = (const f16*)Ap;
      int sm = t >> 2, sk = (t & 3) * 8;
      f16x8 av;
      if (row0 + sm < M) av = *(const f16x8*)(A + (size_t)(row0 + sm) * K + k0 + sk);
      else { for (int q = 0; q < 8; ++q) av[q] = (f16)0.0f; }
      *(f16x8*)&As[sm][sk] = av;
    } else {
      const float* A = (const float*)Ap;
#pragma unroll
      for (int u0 = 0; u0 < 2; ++u0) {
        int u = t + u0 * 256;
        int m = u >> 3, c4 = (u & 7) * 4;
        float4 av = make_float4(0.f, 0.f, 0.f, 0.f);
        if (row0 + m < M) av = *(const float4*)(A + (size_t)(row0 + m) * K + k0 + c4);
        f16x4 hv;
        hv[0] = (f16)av.x; hv[1] = (f16)av.y; hv[2] = (f16)av.z; hv[3] = (f16)av.w;
        *(f16x4*)&As[m][c4] = hv;
      }
    }
#pragma unroll
    for (int u0 = 0; u0 < 2; ++u0) {
      int u = t + u0 * 256;
      int k = u >> 4, n4 = (u & 15) * 4;
      float4 wv = *(const float4*)(W + (size_t)(k0 + k) * N + col0 + n4);
      Bs[n4 + 0][k] = (f16)wv.x;
      Bs[n4 + 1][k] = (f16)wv.y;
      Bs[n4 + 2][k] = (f16)wv.z;
      Bs[n4 + 3][k] = (f16)wv.w;
    }
    __syncthreads();
    f16x8 af[2], bfr[2];
#pragma unroll
    for (int tr = 0; tr < 2; ++tr)
      af[tr] = *(const f16x8*)&As[rw * 32 + tr * 16 + lr][quad * 8];
#pragma unroll
    for (int tc = 0; tc < 2; ++tc)
      bfr[tc] = *(const f16x8*)&Bs[cw * 32 + tc * 16 + lr][quad * 8];
#pragma unroll
    for (int tr = 0; tr < 2; ++tr)
#pragma unroll
      for (int tc = 0; tc < 2; ++tc)
        acc[tr][tc] = __builtin_amdgcn_mfma_f32_16x16x32_f16(af[tr], bfr[tc], acc[tr][tc], 0, 0, 0);
    __syncthreads();
  }
#pragma unroll
  for (int tc = 0; tc < 2; ++tc) {
    int col = col0 + cw * 32 + tc * 16 + lr;
    float bb = bias ? bias[col] : 0.0f;
#pragma unroll
    for (int tr = 0; tr < 2; ++tr) {
#pragma unroll
      for (int r = 0; r < 4; ++r) {
        int row = row0 + rw * 32 + tr * 16 + quad * 4 + r;
        if (row < M) {
          float x = acc[tr][tc][r] + bb;
          if (rowscale) x *= rowscale[row];
          if (SILU) x = silu_f(x);
          size_t o = (size_t)row * N + col;
          if (OUT == 0) ((float*)Cout)[o] = x;
          else          ((f16*)Cout)[o] = (f16)x;
        }
      }
    }
  }
}

// ---------------- dual-weight f16 MFMA GEMM: C1 = A@W1, C2 = A@W2 (fp32 A/out) ----------------
__global__ __launch_bounds__(256) void gemm_dual_kernel(
    const float* __restrict__ A, const float* __restrict__ W1,
    const float* __restrict__ W2, float* __restrict__ C1, float* __restrict__ C2,
    int M, int N, int K)
{
  __shared__ f16 As[64][40];
  __shared__ f16 Bs1[64][40];
  __shared__ f16 Bs2[64][40];
  int t = threadIdx.x;
  int wave = t >> 6, lane = t & 63;
  int rw = wave & 1, cw = wave >> 1;
  int lr = lane & 15, quad = lane >> 4;
  int row0 = blockIdx.x * 64, col0 = blockIdx.y * 64;
  floatx4 acc1[2][2] = {};
  floatx4 acc2[2][2] = {};
  for (int k0 = 0; k0 < K; k0 += 32) {
#pragma unroll
    for (int u0 = 0; u0 < 2; ++u0) {
      int u = t + u0 * 256;
      int m = u >> 3, c4 = (u & 7) * 4;
      float4 av = make_float4(0.f, 0.f, 0.f, 0.f);
      if (row0 + m < M) av = *(const float4*)(A + (size_t)(row0 + m) * K + k0 + c4);
      f16x4 hv;
      hv[0] = (f16)av.x; hv[1] = (f16)av.y; hv[2] = (f16)av.z; hv[3] = (f16)av.w;
      *(f16x4*)&As[m][c4] = hv;
    }
#pragma unroll
    for (int u0 = 0; u0 < 2; ++u0) {
      int u = t + u0 * 256;
      int k = u >> 4, n4 = (u & 15) * 4;
      float4 wv = *(const float4*)(W1 + (size_t)(k0 + k) * N + col0 + n4);
      Bs1[n4 + 0][k] = (f16)wv.x;
      Bs1[n4 + 1][k] = (f16)wv.y;
      Bs1[n4 + 2][k] = (f16)wv.z;
      Bs1[n4 + 3][k] = (f16)wv.w;
      float4 xv = *(const float4*)(W2 + (size_t)(k0 + k) * N + col0 + n4);
      Bs2[n4 + 0][k] = (f16)xv.x;
      Bs2[n4 + 1][k] = (f16)xv.y;
      Bs2[n4 + 2][k] = (f16)xv.z;
      Bs2[n4 + 3][k] = (f16)xv.w;
    }
    __syncthreads();
    f16x8 af[2], b1[2], b2[2];
#pragma unroll
    for (int tr = 0; tr < 2; ++tr)
      af[tr] = *(const f16x8*)&As[rw * 32 + tr * 16 + lr][quad * 8];
#pragma unroll
    for (int tc = 0; tc < 2; ++tc) {
      b1[tc] = *(const f16x8*)&Bs1[cw * 32 + tc * 16 + lr][quad * 8];
      b2[tc] = *(const f16x8*)&Bs2[cw * 32 + tc * 16 + lr][quad * 8];
    }
#pragma unroll
    for (int tr = 0; tr < 2; ++tr)
#pragma unroll
      for (int tc = 0; tc < 2; ++tc) {
        acc1[tr][tc] = __builtin_amdgcn_mfma_f32_16x16x32_f16(af[tr], b1[tc], acc1[tr][tc], 0, 0, 0);
        acc2[tr][tc] = __builtin_amdgcn_mfma_f32_16x16x32_f16(af[tr], b2[tc], acc2[tr][tc], 0, 0, 0);
      }
    __syncthreads();
  }
#pragma unroll
  for (int tc = 0; tc < 2; ++tc) {
    int col = col0 + cw * 32 + tc * 16 + lr;
#pragma unroll
    for (int tr = 0; tr < 2; ++tr) {
#pragma unroll
      for (int r = 0; r < 4; ++r) {
        int row = row0 + rw * 32 + tr * 16 + quad * 4 + r;
        if (row < M) {
          C1[(size_t)row * N + col] = acc1[tr][tc][r];
          C2[(size_t)row * N + col] = acc2[tr][tc][r];
        }
      }
    }
  }
}

// ---------------- MFMA-ws message kernel, TWO-PASS (atomics never between loads) ----------------
// r4 diagnosis: conditional atomicAdd flushes interleaved between pipelined
// loads -> vmcnt not statically known -> conservative drains -> 900 cy/edge.
// Pass 1: ONLY global loads (addresses from register pij[], no atomics);
// results staged in thread-private LDS slots (ph bits pass through LDS
// LOSSLESSLY - r7's bug was rounding inv=ph*ws to f16 here; now the f32
// multiply happens at use in pass 2, numerically identical to r4).
// Pass 2: accumulate from LDS + segment flush; atomics fire-and-forget.
#define MEPB 32
__global__ __launch_bounds__(384, 4) void message_kernel(
    const int2* __restrict__ ij_s, const float* __restrict__ unit_s,
    const f16* __restrict__ rbf_h, const f16* __restrict__ dwf,
    const f16* __restrict__ phi_h, const f16* __restrict__ vh,
    float* __restrict__ s, float* __restrict__ v, int E)
{
  __shared__ f16 rbfA[MEPB][40];
  __shared__ f16 wsT[384][38];      // ws from MFMA; overwritten with ph in pass 1
  __shared__ f16 vjL[3][128][34];   // g0 per-thread vj slots
  __shared__ int2 ijL[MEPB];
  __shared__ float unitL[MEPB * 3];
  int t = threadIdx.x;
  int wave = t >> 6, lane = t & 63;
  int e_lo = blockIdx.x * MEPB;
  if (e_lo >= E) return;
  int e_hi = (e_lo + MEPB < E) ? e_lo + MEPB : E;
  int cnt = e_hi - e_lo;

  // ---- B fragments: 4 col-tiles per wave, from frag-ordered dwf ----
  f16x8 bf[4];
#pragma unroll
  for (int i = 0; i < 4; ++i) {
    int ct = wave * 4 + i;
    bf[i] = *(const f16x8*)(dwf + ((size_t)ct * 64 + lane) * 8);
  }
  // ---- stage rbf rows / ij / unit ----
  if (t < MEPB * 4) {
    int r = t >> 2, c8 = (t & 3) * 8;
    f16x8 rv;
    if (e_lo + r < E) rv = *(const f16x8*)(rbf_h + (size_t)(e_lo + r) * 32 + c8);
    else { for (int q = 0; q < 8; ++q) rv[q] = (f16)0.0f; }
    *(f16x8*)&rbfA[r][c8] = rv;
  }
  if (t < cnt) ijL[t] = ij_s[e_lo + t];
  if (t < cnt * 3) unitL[t] = unit_s[(size_t)e_lo * 3 + t];
  __syncthreads();

  // ---- MFMA: 2 row-tiles x 4 col-tiles per wave ----
  int lr = lane & 15, quad = lane >> 4;
  f16x8 af[2];
#pragma unroll
  for (int tr = 0; tr < 2; ++tr)
    af[tr] = *(const f16x8*)&rbfA[tr * 16 + lr][quad * 8];
  floatx4 acc[2][4] = {};
#pragma unroll
  for (int tr = 0; tr < 2; ++tr)
#pragma unroll
    for (int i = 0; i < 4; ++i)
      acc[tr][i] = __builtin_amdgcn_mfma_f32_16x16x32_f16(af[tr], bf[i], acc[tr][i], 0, 0, 0);
  // C/D layout: col = lane&15 (within tile), row = quad*4 + r -> write transposed
#pragma unroll
  for (int tr = 0; tr < 2; ++tr)
#pragma unroll
    for (int i = 0; i < 4; ++i) {
      int col = (wave * 4 + i) * 16 + lr;
      int er = tr * 16 + quad * 4;
      f16x2 lo2, hi2;
      lo2[0] = (f16)acc[tr][i][0]; lo2[1] = (f16)acc[tr][i][1];
      hi2[0] = (f16)acc[tr][i][2]; hi2[1] = (f16)acc[tr][i][3];
      *(f16x2*)&wsT[col][er]     = lo2;
      *(f16x2*)&wsT[col][er + 2] = hi2;
    }
  __syncthreads();

  // ---- preload ij (packed) and ws into registers: statically indexed ----
  int g = t >> 7, f = t & 127;
  int pij[MEPB];
#pragma unroll
  for (int e = 0; e < MEPB; ++e) {
    int ee = (e < cnt) ? e : (cnt - 1);
    pij[e] = (ijL[ee].x << 16) | (ijL[ee].y & 0xFFFF);
  }
  f16 wsr[MEPB];
#pragma unroll
  for (int e = 0; e < MEPB; ++e) wsr[e] = wsT[t][e];

  // ---- PASS 1: pure global gather -> LDS (no atomics; ph stored bit-exact) ----
#pragma unroll
  for (int e = 0; e < MEPB; ++e) {
    if (e < cnt) {
      int j = pij[e] & 0xFFFF;
      wsT[t][e] = phi_h[(size_t)j * 384 + t];    // ph bits, lossless
      if (g == 0) {
        const f16* vp = vh + (size_t)j * 384 + f;
        vjL[0][f][e] = vp[0];
        vjL[1][f][e] = vp[128];
        vjL[2][f][e] = vp[256];
      }
    }
  }
  __syncthreads();   // drains loads; pass 2's atomics start with clean counters

  // ---- PASS 2: accumulate from LDS + segment flush (atomics fire-and-forget) ----
  float a0 = 0.f, a1 = 0.f, a2 = 0.f;
  int prev_i = -1;
#pragma unroll
  for (int e = 0; e < MEPB; ++e) {
    if (e < cnt) {
      int i = pij[e] >> 16;
      if (i != prev_i) {
        if (prev_i >= 0) {
          if (g == 1) {
            atomicAdd(s + (size_t)prev_i * 128 + f, a0);
          } else {
            float* vb = v + (size_t)prev_i * 384 + f;
            atomicAdd(vb, a0);
            atomicAdd(vb + 128, a1);
            atomicAdd(vb + 256, a2);
          }
          a0 = a1 = a2 = 0.f;
        }
        prev_i = i;
      }
      float inv = (float)wsT[t][e] * (float)wsr[e];   // f32 product at use (r4 numerics)
      if (g == 0) {
        a0 = fmaf(inv, (float)vjL[0][f][e], a0);
        a1 = fmaf(inv, (float)vjL[1][f][e], a1);
        a2 = fmaf(inv, (float)vjL[2][f][e], a2);
      } else if (g == 1) {
        a0 += inv;
      } else {
        a0 = fmaf(inv, unitL[3 * e + 0], a0);
        a1 = fmaf(inv, unitL[3 * e + 1], a1);
        a2 = fmaf(inv, unitL[3 * e + 2], a2);
      }
    }
  }
  if (prev_i >= 0) {
    if (g == 1) {
      atomicAdd(s + (size_t)prev_i * 128 + f, a0);
    } else {
      float* vb = v + (size_t)prev_i * 384 + f;
      atomicAdd(vb, a0);
      atomicAdd(vb + 128, a1);
      atomicAdd(vb + 256, a2);
    }
  }
}

// ---------------- s_stack = [s, ||v_v||] (f16 out) ----------------
__global__ __launch_bounds__(256) void stack_kernel(
    const float* __restrict__ s, const float* __restrict__ v_v,
    f16* __restrict__ s_stack, int N)
{
  int idx = blockIdx.x * 256 + threadIdx.x;
  if (idx >= N * 128) return;
  int n = idx >> 7, g = idx & 127;
  float a = v_v[(size_t)n * 384 + g];
  float b = v_v[(size_t)n * 384 + 128 + g];
  float c = v_v[(size_t)n * 384 + 256 + g];
  s_stack[(size_t)n * 256 + g] = (f16)s[idx];
  s_stack[(size_t)n * 256 + 128 + g] = (f16)sqrtf(a * a + b * b + c * c + EPS_F);
}

// ---------------- gated update of s, v (+ f16 mirrors for next-layer reads) ----------------
__global__ __launch_bounds__(256) void apply_kernel(
    float* __restrict__ s, f16* __restrict__ s_h,
    float* __restrict__ v, f16* __restrict__ v_h,
    const float* __restrict__ u_v, const float* __restrict__ v_v,
    const float* __restrict__ sp, int N)
{
  int idx = blockIdx.x * 256 + threadIdx.x;
  if (idx >= N * 128) return;
  int n = idx >> 7, g = idx & 127;
  float sp0 = sp[(size_t)n * 384 + g];
  float sp1 = sp[(size_t)n * 384 + 128 + g];
  float sp2 = sp[(size_t)n * 384 + 256 + g];
  float dot = 0.f;
#pragma unroll
  for (int c = 0; c < 3; ++c) {
    size_t o = (size_t)n * 384 + c * 128 + g;
    float uv = u_v[o];
    float vn = fmaf(uv, sp0, v[o]);
    v[o] = vn;
    v_h[o] = (f16)vn;
    dot = fmaf(uv, v_v[o], dot);
  }
  float sn = s[idx] + dot * sp1 + sp2;
  s[idx] = sn;
  s_h[idx] = (f16)sn;
}

// ---------------- fused f16 MFMA readout (unsorted edges; register-prefetched gathers) ----------------
__global__ __launch_bounds__(256) void readout_gemm_kernel(
    const int* __restrict__ nbr, const float* __restrict__ xyz,
    const f16* __restrict__ s_h, const f16* __restrict__ w1t,
    const float* __restrict__ b1, const float* __restrict__ w2,
    const float* __restrict__ b2, float* __restrict__ out, int E)
{
  __shared__ f16 As[64][40];
  __shared__ f16 Bs[64][40];
  __shared__ float red[2][64];
  __shared__ int ijc[64][2];
  int t = threadIdx.x;
  int wave = t >> 6, lane = t & 63;
  int rw = wave & 1, cw = wave >> 1;
  int lr = lane & 15, quad = lane >> 4;
  int e0b = blockIdx.x * 64;
  if (t < 64) {
    int e = e0b + t;
    if (e < E) { ijc[t][0] = nbr[2 * e]; ijc[t][1] = nbr[2 * e + 1]; }
    else { ijc[t][0] = 0; ijc[t][1] = 0; }
  }
  __syncthreads();
  int m = t >> 2;             // one row (edge) per thread
  int c8 = (t & 3) * 8;       // 8 features within 32-k window
  int im = ijc[m][0], jm = ijc[m][1];
  bool okm = (e0b + m) < E;
  // prefetch all 8 row-segments (4 windows x i/j) - independent loads in flight
  f16x8 xa[4], ya[4];
  if (okm) {
#pragma unroll
    for (int w = 0; w < 4; ++w) {
      xa[w] = *(const f16x8*)(s_h + (size_t)im * 128 + w * 32 + c8);
      ya[w] = *(const f16x8*)(s_h + (size_t)jm * 128 + w * 32 + c8);
    }
  } else {
#pragma unroll
    for (int w = 0; w < 4; ++w)
      for (int q = 0; q < 8; ++q) { xa[w][q] = (f16)0.0f; ya[w][q] = (f16)0.0f; }
  }
  floatx4 acc[2][2] = {};
#pragma unroll
  for (int w = 0; w < 4; ++w) {
    *(f16x8*)&As[m][c8] = xa[w] + ya[w];
    {
      int sm = t >> 2, sk = (t & 3) * 8;
      *(f16x8*)&Bs[sm][sk] = *(const f16x8*)(w1t + (size_t)sm * 128 + w * 32 + sk);
    }
    __syncthreads();
    f16x8 af[2], bfr[2];
#pragma unroll
    for (int tr = 0; tr < 2; ++tr)
      af[tr] = *(const f16x8*)&As[rw * 32 + tr * 16 + lr][quad * 8];
#pragma unroll
    for (int tc = 0; tc < 2; ++tc)
      bfr[tc] = *(const f16x8*)&Bs[cw * 32 + tc * 16 + lr][quad * 8];
#pragma unroll
    for (int tr = 0; tr < 2; ++tr)
#pragma unroll
      for (int tc = 0; tc < 2; ++tc)
        acc[tr][tc] = __builtin_amdgcn_mfma_f32_16x16x32_f16(af[tr], bfr[tc], acc[tr][tc], 0, 0, 0);
    __syncthreads();
  }
  float b1v[2], w2v[2];
#pragma unroll
  for (int tc = 0; tc < 2; ++tc) {
    int col = cw * 32 + tc * 16 + lr;
    b1v[tc] = b1[col];
    w2v[tc] = w2[col];
  }
#pragma unroll
  for (int tr = 0; tr < 2; ++tr) {
#pragma unroll
    for (int r = 0; r < 4; ++r) {
      float p = 0.f;
#pragma unroll
      for (int tc = 0; tc < 2; ++tc)
        p += silu_f(acc[tr][tc][r] + b1v[tc]) * w2v[tc];
#pragma unroll
      for (int ofs = 1; ofs < 16; ofs <<= 1) p += __shfl_xor(p, ofs, 64);
      if (lr == 0) red[cw][rw * 32 + tr * 16 + quad * 4 + r] = p;
    }
  }
  __syncthreads();
  if (t < 64) {
    int e = e0b + t;
    if (e < E) {
      float fs = red[0][t] + red[1][t] + b2[0];
      int i = ijc[t][0], j = ijc[t][1];
      float dx = xyz[3 * i + 0] - xyz[3 * j + 0];
      float dy = xyz[3 * i + 1] - xyz[3 * j + 1];
      float dz = xyz[3 * i + 2] - xyz[3 * j + 2];
      float dis = sqrtf(dx * dx + dy * dy + dz * dz);  // no EPS here (matches ref)
      float sc = fs / dis;
      float fx = sc * dx, fy = sc * dy, fz = sc * dz;
      atomicAdd(out + (size_t)i * 3 + 0, fx);
      atomicAdd(out + (size_t)i * 3 + 1, fy);
      atomicAdd(out + (size_t)i * 3 + 2, fz);
      atomicAdd(out + (size_t)j * 3 + 0, -fx);
      atomicAdd(out + (size_t)j * 3 + 1, -fy);
      atomicAdd(out + (size_t)j * 3 + 2, -fz);
    }
  }
}

extern "C" void kernel_launch(void* const* d_in, const int* in_sizes, int n_in,
                              void* d_out, int out_size, void* d_ws, size_t ws_size,
                              hipStream_t stream) {
  const float* xyz    = (const float*)d_in[0];
  const int*   z      = (const int*)d_in[1];
  const int*   nbr    = (const int*)d_in[2];
  const float* embed  = (const float*)d_in[3];
  const float* msg_w1 = (const float*)d_in[4];
  const float* msg_b1 = (const float*)d_in[5];
  const float* msg_w2 = (const float*)d_in[6];
  const float* msg_b2 = (const float*)d_in[7];
  const float* dist_w = (const float*)d_in[8];
  const float* dist_b = (const float*)d_in[9];
  const float* upd_u  = (const float*)d_in[10];
  const float* upd_v  = (const float*)d_in[11];
  const float* upd_w1 = (const float*)d_in[12];
  const float* upd_b1 = (const float*)d_in[13];
  const float* upd_w2 = (const float*)d_in[14];
  const float* upd_b2 = (const float*)d_in[15];
  const float* ero_w1 = (const float*)d_in[16];
  const float* ero_b1 = (const float*)d_in[17];
  const float* ero_w2 = (const float*)d_in[18];
  const float* ero_b2 = (const float*)d_in[19];

  const int N = in_sizes[1];      // 10000
  const int E = in_sizes[2] / 2;  // 160000
  const int L = 3;

  char* ws = (char*)d_ws;
  size_t off = 0;
  auto alloc = [&](size_t bytes) -> void* {
    void* p = ws + off;
    off += (bytes + 255) & ~(size_t)255;
    return p;
  };
  float* unit_s = (float*)alloc((size_t)E * 3 * 4);
  f16*   rbf_h  = (f16*)alloc((size_t)E * 32 * 2);
  int2*  ij_s   = (int2*)alloc((size_t)E * 8);
  int*   order  = (int*)alloc((size_t)E * 4);
  float* s      = (float*)alloc((size_t)N * 128 * 4);
  f16*   s_h    = (f16*)alloc((size_t)N * 128 * 2);
  float* vA     = (float*)alloc((size_t)N * 384 * 4);
  f16*   vhA    = (f16*)alloc((size_t)N * 384 * 2);
  f16*   phi_h  = (f16*)alloc((size_t)N * 384 * 2);
  f16*   w1t    = (f16*)alloc((size_t)64 * 128 * 2);
  f16*   dwf    = (f16*)alloc((size_t)3 * 24 * 64 * 8 * 2);
  int*   histx  = (int*)alloc((size_t)(N + 1) * 4);
  int*   startp = (int*)alloc((size_t)(N + 1) * 4);
  int*   cursor = (int*)alloc((size_t)N * 4);
  float* u_v    = (float*)alloc((size_t)N * 384 * 4);
  float* v_v    = (float*)alloc((size_t)N * 384 * 4);
  float* sp     = (float*)alloc((size_t)N * 384 * 4);
  f16*   sstk_h = (f16*)alloc((size_t)N * 256 * 2);
  f16*   h_h    = (f16*)alloc((size_t)N * 128 * 2);

  auto cdiv = [](int a, int b) { return (a + b - 1) / b; };

  // ---- setup: deterministic CSR + weight pre-pack ----
  hipMemsetAsync(vA, 0, (size_t)N * 384 * 4, stream);
  hipMemsetAsync(vhA, 0, (size_t)N * 384 * 2, stream);
  hipMemsetAsync(histx, 0, (size_t)(N + 1) * 4, stream);
  hist_kernel<<<cdiv(E, 256), 256, 0, stream>>>(nbr, histx, E);
  scan_kernel<<<1, 1024, 0, stream>>>(histx, startp, cursor, N);
  scatter_id_kernel<<<cdiv(E, 256), 256, 0, stream>>>(nbr, cursor, order, E);
  segsort_kernel<<<cdiv(N, 4), 256, 0, stream>>>(order, startp, N);
  geom_fill_kernel<<<cdiv(E, 256), 256, 0, stream>>>(
      order, nbr, xyz, ij_s, unit_s, rbf_h, E);
  embed_kernel<<<cdiv(N * 128, 256), 256, 0, stream>>>(z, embed, s, s_h, N);
  w1t_kernel<<<cdiv(64 * 128, 256), 256, 0, stream>>>(ero_w1, w1t);
  dwfrag_kernel<<<cdiv(3 * 24 * 64 * 8, 256), 256, 0, stream>>>(dist_w, dist_b, dwf);

  for (int l = 0; l < L; ++l) {
    // phi = silu(s @ msg_w1 + b1) @ msg_w2 + b2  -> f16 (A read from f16 mirror)
    gemm_kernel<true, 1, true><<<dim3(cdiv(N, 64), 2), 256, 0, stream>>>(
        s_h, msg_w1 + (size_t)l * 128 * 128, msg_b1 + (size_t)l * 128, nullptr, h_h, N, 128, 128);
    gemm_kernel<false, 1, true><<<dim3(cdiv(N, 64), 6), 256, 0, stream>>>(
        h_h, msg_w2 + (size_t)l * 128 * 384, msg_b2 + (size_t)l * 384, nullptr, phi_h, N, 384, 128);
    // MFMA-ws message; atomic flush into s / v (in place)
    message_kernel<<<cdiv(E, MEPB), 384, 0, stream>>>(
        ij_s, unit_s, rbf_h, dwf + (size_t)l * 24 * 64 * 8,
        phi_h, vhA, s, vA, E);
    // update block
    gemm_dual_kernel<<<dim3(cdiv(N * 3, 64), 2), 256, 0, stream>>>(
        vA, upd_u + (size_t)l * 128 * 128, upd_v + (size_t)l * 128 * 128,
        u_v, v_v, N * 3, 128, 128);
    stack_kernel<<<cdiv(N * 128, 256), 256, 0, stream>>>(s, v_v, sstk_h, N);
    gemm_kernel<true, 1, true><<<dim3(cdiv(N, 64), 2), 256, 0, stream>>>(
        sstk_h, upd_w1 + (size_t)l * 256 * 128, upd_b1 + (size_t)l * 128, nullptr, h_h, N, 128, 256);
    gemm_kernel<false, 0, true><<<dim3(cdiv(N, 64), 6), 256, 0, stream>>>(
        h_h, upd_w2 + (size_t)l * 128 * 384, upd_b2 + (size_t)l * 384, nullptr, sp, N, 384, 128);
    apply_kernel<<<cdiv(N * 128, 256), 256, 0, stream>>>(
        s, s_h, vA, vhA, u_v, v_v, sp, N);
  }

  // fused f16 MFMA readout (unsorted edges, register-prefetched gathers)
  hipMemsetAsync(d_out, 0, (size_t)out_size * 4, stream);
  readout_gemm_kernel<<<cdiv(E, 64), 256, 0, stream>>>(
      nbr, xyz, s_h, w1t, ero_b1, ero_w2, ero_b2, (float*)d_out, E);
}

// Round 9
// 909.840 us; speedup vs baseline: 1.9038x; 1.9038x over previous
//
#include <hip/hip_runtime.h>
#include <math.h>

#define EPS_F 1e-15f
#define NRBF 20
#define CUTOFF_F 5.0f
#define PI_F 3.14159265358979323846f

typedef unsigned short u16;
typedef _Float16 f16;
typedef f16 f16x8 __attribute__((ext_vector_type(8)));
typedef f16 f16x4 __attribute__((ext_vector_type(4)));
typedef f16 f16x2 __attribute__((ext_vector_type(2)));
typedef float floatx4 __attribute__((ext_vector_type(4)));

__device__ __forceinline__ float silu_f(float x) { return x / (1.0f + expf(-x)); }

// async global->LDS, 16B per lane, wave-uniform LDS base + lane*16
__device__ __forceinline__ void gload_lds16(const void* g, void* l) {
  __builtin_amdgcn_global_load_lds(
      (const __attribute__((address_space(1))) unsigned int*)g,
      (__attribute__((address_space(3))) unsigned int*)l, 16, 0, 0);
}

// ---------------- counting sort: histogram + scan ----------------
__global__ __launch_bounds__(256) void hist_kernel(
    const int* __restrict__ nbr, int* __restrict__ hist, int E)
{
  int e = blockIdx.x * 256 + threadIdx.x;
  if (e >= E) return;
  atomicAdd(hist + nbr[2 * e], 1);
}

// single-block exclusive scan, wave-shfl based (few barriers)
__global__ __launch_bounds__(1024) void scan_kernel(
    const int* __restrict__ hist, int* __restrict__ start,
    int* __restrict__ cursor, int N)
{
  __shared__ int wsum[16];
  __shared__ int carry_s;
  int tid = threadIdx.x;
  int lane = tid & 63, wid = tid >> 6;
  if (tid == 0) carry_s = 0;
  __syncthreads();
  for (int base = 0; base < N; base += 1024) {
    int x = (base + tid < N) ? hist[base + tid] : 0;
    int v = x;
#pragma unroll
    for (int o = 1; o < 64; o <<= 1) {
      int t2 = __shfl_up(v, o, 64);
      if (lane >= o) v += t2;
    }
    if (lane == 63) wsum[wid] = v;
    __syncthreads();
    if (tid < 16) {
      int w = wsum[tid];
#pragma unroll
      for (int o = 1; o < 16; o <<= 1) {
        int t2 = __shfl_up(w, o, 64);
        if (tid >= o) w += t2;
      }
      wsum[tid] = w;
    }
    __syncthreads();
    int wbase = (wid == 0) ? 0 : wsum[wid - 1];
    int incl = v + wbase;
    int carry = carry_s;
    if (base + tid < N) {
      int ex = carry + incl - x;
      start[base + tid] = ex;
      cursor[base + tid] = ex;
    }
    __syncthreads();
    if (tid == 1023) carry_s = carry + incl;
    __syncthreads();
  }
  if (tid == 0) start[N] = carry_s;
}

// ---------------- scatter edge IDs ----------------
__global__ __launch_bounds__(256) void scatter_id_kernel(
    const int* __restrict__ nbr, int* __restrict__ cursor,
    int* __restrict__ order, int E)
{
  int e = blockIdx.x * 256 + threadIdx.x;
  if (e >= E) return;
  int pos = atomicAdd(cursor + nbr[2 * e], 1);
  order[pos] = e;
}

// ---------------- canonicalize: wave rank-sort of each atom's segment ----------------
__global__ __launch_bounds__(256) void segsort_kernel(
    int* __restrict__ order, const int* __restrict__ start, int N)
{
  int wi = blockIdx.x * 4 + (threadIdx.x >> 6);
  int lane = threadIdx.x & 63;
  if (wi >= N) return;
  int s0 = start[wi], s1 = start[wi + 1];
  int len = s1 - s0;
  if (len <= 1) return;
  if (len <= 64) {
    int id = (lane < len) ? order[s0 + lane] : 0x7FFFFFFF;
    int rank = 0;
#pragma unroll
    for (int k = 0; k < 64; ++k) {
      int other = __shfl(id, k, 64);
      rank += (other < id) ? 1 : 0;
    }
    if (lane < len) order[s0 + rank] = id;
  } else if (lane == 0) {
    for (int a = s0 + 1; a < s1; ++a) {
      int key = order[a];
      int b = a - 1;
      while (b >= s0 && order[b] > key) { order[b + 1] = order[b]; --b; }
      order[b + 1] = key;
    }
  }
}

// ---------------- geometry gather-fill (deterministic) ----------------
// rbf_h row layout (32 f16): slots 0..19 = sin(k_n d)/d * env   (env pre-folded)
//                            slot  20    = env
//                            slots 21..31 = 0
__global__ __launch_bounds__(256) void geom_fill_kernel(
    const int* __restrict__ order, const int* __restrict__ nbr,
    const float* __restrict__ xyz, int2* __restrict__ ij_s,
    float* __restrict__ unit_s, f16* __restrict__ rbf_h, int E)
{
  int p = blockIdx.x * 256 + threadIdx.x;
  if (p >= E) return;
  int e = order[p];
  int i = nbr[2 * e], j = nbr[2 * e + 1];
  float dx = xyz[3 * j + 0] - xyz[3 * i + 0];
  float dy = xyz[3 * j + 1] - xyz[3 * i + 1];
  float dz = xyz[3 * j + 2] - xyz[3 * i + 2];
  float d2 = dx * dx + dy * dy + dz * dz + 3.0f * EPS_F;  // ref adds EPS per comp
  float d = sqrtf(d2);
  float inv_d = 1.0f / d;
  ij_s[p] = make_int2(i, j);
  unit_s[3 * p + 0] = dx * inv_d;
  unit_s[3 * p + 1] = dy * inv_d;
  unit_s[3 * p + 2] = dz * inv_d;
  float x = d * (PI_F / CUTOFF_F);
  float s1, c1;
  __sincosf(x, &s1, &c1);
  float envv = (d < CUTOFF_F) ? 0.5f * (c1 + 1.0f) : 0.0f;
  f16 tmp[32];
  float two_c = 2.0f * c1;
  float env_inv_d = envv * inv_d;
  float sp = 0.0f, sn = s1;           // Chebyshev recurrence for sin(n*x)
  tmp[0] = (f16)(sn * env_inv_d);
#pragma unroll
  for (int n = 1; n < NRBF; ++n) {
    float nx = two_c * sn - sp;
    sp = sn; sn = nx;
    tmp[n] = (f16)(sn * env_inv_d);
  }
  tmp[NRBF] = (f16)envv;
#pragma unroll
  for (int n = NRBF + 1; n < 32; ++n) tmp[n] = (f16)0.0f;
#pragma unroll
  for (int g = 0; g < 4; ++g)
    *(f16x8*)(rbf_h + (size_t)p * 32 + g * 8) = *(f16x8*)&tmp[g * 8];
}

// ---------------- pre-pack dwx = [dist_w; dist_b; 0] into MFMA B-fragment order ----------------
__global__ __launch_bounds__(256) void dwfrag_kernel(
    const float* __restrict__ dw, const float* __restrict__ db,
    f16* __restrict__ dwf)
{
  int idx = blockIdx.x * 256 + threadIdx.x;
  if (idx >= 3 * 24 * 64 * 8) return;
  int q = idx & 7;
  int lane = (idx >> 3) & 63;
  int ct = (idx >> 9) % 24;
  int l = idx / (24 * 64 * 8);
  int k = (lane >> 4) * 8 + q;
  int col = ct * 16 + (lane & 15);
  float val = 0.f;
  if (k < NRBF) val = dw[(size_t)l * NRBF * 384 + (size_t)k * 384 + col];
  else if (k == NRBF) val = db[(size_t)l * 384 + col];
  dwf[idx] = (f16)val;
}

// ---------------- s = embed[z] (fp32 + f16 mirror) ----------------
__global__ __launch_bounds__(256) void embed_kernel(
    const int* __restrict__ z, const float* __restrict__ embed,
    float* __restrict__ s, f16* __restrict__ s_h, int N)
{
  int idx = blockIdx.x * 256 + threadIdx.x;
  if (idx >= N * 128) return;
  int n = idx >> 7, f = idx & 127;
  float x = embed[z[n] * 128 + f];
  s[idx] = x;
  s_h[idx] = (f16)x;
}

__global__ __launch_bounds__(256) void w1t_kernel(
    const float* __restrict__ w1, f16* __restrict__ w1t)
{
  int idx = blockIdx.x * 256 + threadIdx.x;
  if (idx >= 64 * 128) return;
  int n = idx >> 7, k = idx & 127;
  w1t[idx] = (f16)w1[(size_t)k * 64 + n];
}

// ---------------- f16 MFMA GEMM ----------------
template <bool SILU, int OUT, bool AH>
__global__ __launch_bounds__(256) void gemm_kernel(
    const void* __restrict__ Ap, const float* __restrict__ W,
    const float* __restrict__ bias, const float* __restrict__ rowscale,
    void* __restrict__ Cout, int M, int N, int K)
{
  __shared__ f16 As[64][40];
  __shared__ f16 Bs[64][40];
  int t = threadIdx.x;
  int wave = t >> 6, lane = t & 63;
  int rw = wave & 1, cw = wave >> 1;
  int lr = lane & 15, quad = lane >> 4;
  int row0 = blockIdx.x * 64, col0 = blockIdx.y * 64;
  floatx4 acc[2][2] = {};
  for (int k0 = 0; k0 < K; k0 += 32) {
    if (AH) {
      const f16* A = (const f16*)Ap;
      int sm = t >> 2, sk = (t & 3) * 8;
      f16x8 av;
      if (row0 + sm < M) av = *(const f16x8*)(A + (size_t)(row0 + sm) * K + k0 + sk);
      else { for (int q = 0; q < 8; ++q) av[q] = (f16)0.0f; }
      *(f16x8*)&As[sm][sk] = av;
    } else {
      const float* A = (const float*)Ap;
#pragma unroll
      for (int u0 = 0; u0 < 2; ++u0) {
        int u = t + u0 * 256;
        int m = u >> 3, c4 = (u & 7) * 4;
        float4 av = make_float4(0.f, 0.f, 0.f, 0.f);
        if (row0 + m < M) av = *(const float4*)(A + (size_t)(row0 + m) * K + k0 + c4);
        f16x4 hv;
        hv[0] = (f16)av.x; hv[1] = (f16)av.y; hv[2] = (f16)av.z; hv[3] = (f16)av.w;
        *(f16x4*)&As[m][c4] = hv;
      }
    }
#pragma unroll
    for (int u0 = 0; u0 < 2; ++u0) {
      int u = t + u0 * 256;
      int k = u >> 4, n4 = (u & 15) * 4;
      float4 wv = *(const float4*)(W + (size_t)(k0 + k) * N + col0 + n4);
      Bs[n4 + 0][k] = (f16)wv.x;
      Bs[n4 + 1][k] = (f16)wv.y;
      Bs[n4 + 2][k] = (f16)wv.z;
      Bs[n4 + 3][k] = (f16)wv.w;
    }
    __syncthreads();
    f16x8 af[2], bfr[2];
#pragma unroll
    for (int tr = 0; tr < 2; ++tr)
      af[tr] = *(const f16x8*)&As[rw * 32 + tr * 16 + lr][quad * 8];
#pragma unroll
    for (int tc = 0; tc < 2; ++tc)
      bfr[tc] = *(const f16x8*)&Bs[cw * 32 + tc * 16 + lr][quad * 8];
#pragma unroll
    for (int tr = 0; tr < 2; ++tr)
#pragma unroll
      for (int tc = 0; tc < 2; ++tc)
        acc[tr][tc] = __builtin_amdgcn_mfma_f32_16x16x32_f16(af[tr], bfr[tc], acc[tr][tc], 0, 0, 0);
    __syncthreads();
  }
#pragma unroll
  for (int tc = 0; tc < 2; ++tc) {
    int col = col0 + cw * 32 + tc * 16 + lr;
    float bb = bias ? bias[col] : 0.0f;
#pragma unroll
    for (int tr = 0; tr < 2; ++tr) {
#pragma unroll
      for (int r = 0; r < 4; ++r) {
        int row = row0 + rw * 32 + tr * 16 + quad * 4 + r;
        if (row < M) {
          float x = acc[tr][tc][r] + bb;
          if (rowscale) x *= rowscale[row];
          if (SILU) x = silu_f(x);
          size_t o = (size_t)row * N + col;
          if (OUT == 0) ((float*)Cout)[o] = x;
          else          ((f16*)Cout)[o] = (f16)x;
        }
      }
    }
  }
}

// ---------------- dual-weight f16 MFMA GEMM: C1 = A@W1, C2 = A@W2 (fp32 A/out) ----------------
__global__ __launch_bounds__(256) void gemm_dual_kernel(
    const float* __restrict__ A, const float* __restrict__ W1,
    const float* __restrict__ W2, float* __restrict__ C1, float* __restrict__ C2,
    int M, int N, int K)
{
  __shared__ f16 As[64][40];
  __shared__ f16 Bs1[64][40];
  __shared__ f16 Bs2[64][40];
  int t = threadIdx.x;
  int wave = t >> 6, lane = t & 63;
  int rw = wave & 1, cw = wave >> 1;
  int lr = lane & 15, quad = lane >> 4;
  int row0 = blockIdx.x * 64, col0 = blockIdx.y * 64;
  floatx4 acc1[2][2] = {};
  floatx4 acc2[2][2] = {};
  for (int k0 = 0; k0 < K; k0 += 32) {
#pragma unroll
    for (int u0 = 0; u0 < 2; ++u0) {
      int u = t + u0 * 256;
      int m = u >> 3, c4 = (u & 7) * 4;
      float4 av = make_float4(0.f, 0.f, 0.f, 0.f);
      if (row0 + m < M) av = *(const float4*)(A + (size_t)(row0 + m) * K + k0 + c4);
      f16x4 hv;
      hv[0] = (f16)av.x; hv[1] = (f16)av.y; hv[2] = (f16)av.z; hv[3] = (f16)av.w;
      *(f16x4*)&As[m][c4] = hv;
    }
#pragma unroll
    for (int u0 = 0; u0 < 2; ++u0) {
      int u = t + u0 * 256;
      int k = u >> 4, n4 = (u & 15) * 4;
      float4 wv = *(const float4*)(W1 + (size_t)(k0 + k) * N + col0 + n4);
      Bs1[n4 + 0][k] = (f16)wv.x;
      Bs1[n4 + 1][k] = (f16)wv.y;
      Bs1[n4 + 2][k] = (f16)wv.z;
      Bs1[n4 + 3][k] = (f16)wv.w;
      float4 xv = *(const float4*)(W2 + (size_t)(k0 + k) * N + col0 + n4);
      Bs2[n4 + 0][k] = (f16)xv.x;
      Bs2[n4 + 1][k] = (f16)xv.y;
      Bs2[n4 + 2][k] = (f16)xv.z;
      Bs2[n4 + 3][k] = (f16)xv.w;
    }
    __syncthreads();
    f16x8 af[2], b1[2], b2[2];
#pragma unroll
    for (int tr = 0; tr < 2; ++tr)
      af[tr] = *(const f16x8*)&As[rw * 32 + tr * 16 + lr][quad * 8];
#pragma unroll
    for (int tc = 0; tc < 2; ++tc) {
      b1[tc] = *(const f16x8*)&Bs1[cw * 32 + tc * 16 + lr][quad * 8];
      b2[tc] = *(const f16x8*)&Bs2[cw * 32 + tc * 16 + lr][quad * 8];
    }
#pragma unroll
    for (int tr = 0; tr < 2; ++tr)
#pragma unroll
      for (int tc = 0; tc < 2; ++tc) {
        acc1[tr][tc] = __builtin_amdgcn_mfma_f32_16x16x32_f16(af[tr], b1[tc], acc1[tr][tc], 0, 0, 0);
        acc2[tr][tc] = __builtin_amdgcn_mfma_f32_16x16x32_f16(af[tr], b2[tc], acc2[tr][tc], 0, 0, 0);
      }
    __syncthreads();
  }
#pragma unroll
  for (int tc = 0; tc < 2; ++tc) {
    int col = col0 + cw * 32 + tc * 16 + lr;
#pragma unroll
    for (int tr = 0; tr < 2; ++tr) {
#pragma unroll
      for (int r = 0; r < 4; ++r) {
        int row = row0 + rw * 32 + tr * 16 + quad * 4 + r;
        if (row < M) {
          C1[(size_t)row * N + col] = acc1[tr][tc][r];
          C2[(size_t)row * N + col] = acc2[tr][tc][r];
        }
      }
    }
  }
}

// ---------------- MFMA-ws message kernel, ASYNC-STAGED gathers ----------------
// r4-r8 lesson: per-thread gather loops serialize (~900 cy/edge) no matter
// how arranged: conditional loads + data-dependent atomics defeat static
// vmcnt counting (m131-m141: source-level pipelining loses).
// Key insight: for edge e, the phi gather phi_h[j*384 + 0..383] is a
// CONTIGUOUS 768B row with wave-uniform base = exactly what
// global_load_lds (width 16) does. 32 phi rows = 24 dwordx4 issues (4/wave,
// unconditional); same for vh. One vmcnt drain at the barrier covers the
// whole batch. Pass 2 (LDS-only + atomics) has no loads to stall.
// LDS: phiL overlays wsT region (ws copied to 16 VGPRs first) -> 57KB,
// 2 blocks/CU.
#define MEPB 32
__global__ __launch_bounds__(384, 3) void message_kernel(
    const int2* __restrict__ ij_s, const float* __restrict__ unit_s,
    const f16* __restrict__ rbf_h, const f16* __restrict__ dwf,
    const f16* __restrict__ phi_h, const f16* __restrict__ vh,
    float* __restrict__ s, float* __restrict__ v, int E)
{
  __shared__ f16 rbfA[MEPB][40];
  __shared__ __align__(16) char ovl[29184];          // wsT[384][38] / phiL[32*384]
  __shared__ __align__(16) f16 vhL[MEPB * 384];      // 24576 B, linear for gload_lds
  __shared__ int2 ijL[MEPB];
  __shared__ float unitL[MEPB * 3];
  f16 (*wsT)[38] = (f16(*)[38])ovl;
  f16* phiL = (f16*)ovl;
  int t = threadIdx.x;
  int wave = t >> 6, lane = t & 63;
  int e_lo = blockIdx.x * MEPB;
  if (e_lo >= E) return;
  int e_hi = (e_lo + MEPB < E) ? e_lo + MEPB : E;
  int cnt = e_hi - e_lo;

  // ---- B fragments: 4 col-tiles per wave, from frag-ordered dwf ----
  f16x8 bf[4];
#pragma unroll
  for (int i = 0; i < 4; ++i) {
    int ct = wave * 4 + i;
    bf[i] = *(const f16x8*)(dwf + ((size_t)ct * 64 + lane) * 8);
  }
  // ---- stage rbf rows / ij (clamped) / unit ----
  if (t < MEPB * 4) {
    int r = t >> 2, c8 = (t & 3) * 8;
    f16x8 rv;
    if (e_lo + r < E) rv = *(const f16x8*)(rbf_h + (size_t)(e_lo + r) * 32 + c8);
    else { for (int q = 0; q < 8; ++q) rv[q] = (f16)0.0f; }
    *(f16x8*)&rbfA[r][c8] = rv;
  }
  if (t < MEPB) {
    int ee = e_lo + t; if (ee >= E) ee = E - 1;
    ijL[t] = ij_s[ee];                       // clamped: async loads always valid
  }
  if (t < MEPB * 3) {
    int uu = e_lo * 3 + t; if (uu >= E * 3) uu = E * 3 - 1;
    unitL[t] = unit_s[uu];
  }
  __syncthreads();

  // ---- MFMA: 2 row-tiles x 4 col-tiles per wave -> wsT ----
  int lr = lane & 15, quad = lane >> 4;
  f16x8 af[2];
#pragma unroll
  for (int tr = 0; tr < 2; ++tr)
    af[tr] = *(const f16x8*)&rbfA[tr * 16 + lr][quad * 8];
  floatx4 acc[2][4] = {};
#pragma unroll
  for (int tr = 0; tr < 2; ++tr)
#pragma unroll
    for (int i = 0; i < 4; ++i)
      acc[tr][i] = __builtin_amdgcn_mfma_f32_16x16x32_f16(af[tr], bf[i], acc[tr][i], 0, 0, 0);
  // C/D layout: col = lane&15 (within tile), row = quad*4 + r -> write transposed
#pragma unroll
  for (int tr = 0; tr < 2; ++tr)
#pragma unroll
    for (int i = 0; i < 4; ++i) {
      int col = (wave * 4 + i) * 16 + lr;
      int er = tr * 16 + quad * 4;
      f16x2 lo2, hi2;
      lo2[0] = (f16)acc[tr][i][0]; lo2[1] = (f16)acc[tr][i][1];
      hi2[0] = (f16)acc[tr][i][2]; hi2[1] = (f16)acc[tr][i][3];
      *(f16x2*)&wsT[col][er]     = lo2;
      *(f16x2*)&wsT[col][er + 2] = hi2;
    }
  __syncthreads();

  // ---- ws row -> registers (statically indexed), then free the wsT region ----
  int g = t >> 7, f = t & 127;
  f16 wsr[MEPB];
#pragma unroll
  for (int e = 0; e < MEPB; ++e) wsr[e] = wsT[t][e];
  __syncthreads();   // everyone done reading wsT before phiL overwrites it

  // ---- ASYNC STAGE: phi rows + vh rows -> LDS via global_load_lds ----
  // 32 rows x 768B = 24576B each; 24 chunks of 1024B; 4 chunks per wave.
  {
    const char* phiB = (const char*)phi_h;
    const char* vhB  = (const char*)vh;
#pragma unroll
    for (int it = 0; it < 4; ++it) {
      int chunk = wave * 4 + it;              // 0..23, wave-uniform
      int flat = chunk * 1024 + lane * 16;    // byte offset, per-lane
      int row = flat / 768;                   // 768%16==0: no straddle
      int bin = flat - row * 768;
      int j = ijL[row].y;
      gload_lds16(phiB + (size_t)j * 768 + bin, (char*)phiL + chunk * 1024);
      gload_lds16(vhB  + (size_t)j * 768 + bin, (char*)vhL  + chunk * 1024);
    }
  }
  __syncthreads();   // single vmcnt drain for the whole batch

  // ---- PASS 2: accumulate from LDS + segment flush (no loads -> atomics free) ----
  float a0 = 0.f, a1 = 0.f, a2 = 0.f;
  int prev_i = -1;
#pragma unroll
  for (int e = 0; e < MEPB; ++e) {
    if (e < cnt) {
      int i = ijL[e].x;
      if (i != prev_i) {
        if (prev_i >= 0) {
          if (g == 1) {
            atomicAdd(s + (size_t)prev_i * 128 + f, a0);
          } else {
            float* vb = v + (size_t)prev_i * 384 + f;
            atomicAdd(vb, a0);
            atomicAdd(vb + 128, a1);
            atomicAdd(vb + 256, a2);
          }
          a0 = a1 = a2 = 0.f;
        }
        prev_i = i;
      }
      float inv = (float)phiL[e * 384 + t] * (float)wsr[e];   // f32 at use (r4 numerics)
      if (g == 0) {
        a0 = fmaf(inv, (float)vhL[e * 384 + f],       a0);
        a1 = fmaf(inv, (float)vhL[e * 384 + 128 + f], a1);
        a2 = fmaf(inv, (float)vhL[e * 384 + 256 + f], a2);
      } else if (g == 1) {
        a0 += inv;
      } else {
        a0 = fmaf(inv, unitL[3 * e + 0], a0);
        a1 = fmaf(inv, unitL[3 * e + 1], a1);
        a2 = fmaf(inv, unitL[3 * e + 2], a2);
      }
    }
  }
  if (prev_i >= 0) {
    if (g == 1) {
      atomicAdd(s + (size_t)prev_i * 128 + f, a0);
    } else {
      float* vb = v + (size_t)prev_i * 384 + f;
      atomicAdd(vb, a0);
      atomicAdd(vb + 128, a1);
      atomicAdd(vb + 256, a2);
    }
  }
}

// ---------------- s_stack = [s, ||v_v||] (f16 out) ----------------
__global__ __launch_bounds__(256) void stack_kernel(
    const float* __restrict__ s, const float* __restrict__ v_v,
    f16* __restrict__ s_stack, int N)
{
  int idx = blockIdx.x * 256 + threadIdx.x;
  if (idx >= N * 128) return;
  int n = idx >> 7, g = idx & 127;
  float a = v_v[(size_t)n * 384 + g];
  float b = v_v[(size_t)n * 384 + 128 + g];
  float c = v_v[(size_t)n * 384 + 256 + g];
  s_stack[(size_t)n * 256 + g] = (f16)s[idx];
  s_stack[(size_t)n * 256 + 128 + g] = (f16)sqrtf(a * a + b * b + c * c + EPS_F);
}

// ---------------- gated update of s, v (+ f16 mirrors for next-layer reads) ----------------
__global__ __launch_bounds__(256) void apply_kernel(
    float* __restrict__ s, f16* __restrict__ s_h,
    float* __restrict__ v, f16* __restrict__ v_h,
    const float* __restrict__ u_v, const float* __restrict__ v_v,
    const float* __restrict__ sp, int N)
{
  int idx = blockIdx.x * 256 + threadIdx.x;
  if (idx >= N * 128) return;
  int n = idx >> 7, g = idx & 127;
  float sp0 = sp[(size_t)n * 384 + g];
  float sp1 = sp[(size_t)n * 384 + 128 + g];
  float sp2 = sp[(size_t)n * 384 + 256 + g];
  float dot = 0.f;
#pragma unroll
  for (int c = 0; c < 3; ++c) {
    size_t o = (size_t)n * 384 + c * 128 + g;
    float uv = u_v[o];
    float vn = fmaf(uv, sp0, v[o]);
    v[o] = vn;
    v_h[o] = (f16)vn;
    dot = fmaf(uv, v_v[o], dot);
  }
  float sn = s[idx] + dot * sp1 + sp2;
  s[idx] = sn;
  s_h[idx] = (f16)sn;
}

// ---------------- fused f16 MFMA readout (unsorted edges; register-prefetched gathers) ----------------
__global__ __launch_bounds__(256) void readout_gemm_kernel(
    const int* __restrict__ nbr, const float* __restrict__ xyz,
    const f16* __restrict__ s_h, const f16* __restrict__ w1t,
    const float* __restrict__ b1, const float* __restrict__ w2,
    const float* __restrict__ b2, float* __restrict__ out, int E)
{
  __shared__ f16 As[64][40];
  __shared__ f16 Bs[64][40];
  __shared__ float red[2][64];
  __shared__ int ijc[64][2];
  int t = threadIdx.x;
  int wave = t >> 6, lane = t & 63;
  int rw = wave & 1, cw = wave >> 1;
  int lr = lane & 15, quad = lane >> 4;
  int e0b = blockIdx.x * 64;
  if (t < 64) {
    int e = e0b + t;
    if (e < E) { ijc[t][0] = nbr[2 * e]; ijc[t][1] = nbr[2 * e + 1]; }
    else { ijc[t][0] = 0; ijc[t][1] = 0; }
  }
  __syncthreads();
  int m = t >> 2;             // one row (edge) per thread
  int c8 = (t & 3) * 8;       // 8 features within 32-k window
  int im = ijc[m][0], jm = ijc[m][1];
  bool okm = (e0b + m) < E;
  // prefetch all 8 row-segments (4 windows x i/j) - independent loads in flight
  f16x8 xa[4], ya[4];
  if (okm) {
#pragma unroll
    for (int w = 0; w < 4; ++w) {
      xa[w] = *(const f16x8*)(s_h + (size_t)im * 128 + w * 32 + c8);
      ya[w] = *(const f16x8*)(s_h + (size_t)jm * 128 + w * 32 + c8);
    }
  } else {
#pragma unroll
    for (int w = 0; w < 4; ++w)
      for (int q = 0; q < 8; ++q) { xa[w][q] = (f16)0.0f; ya[w][q] = (f16)0.0f; }
  }
  floatx4 acc[2][2] = {};
#pragma unroll
  for (int w = 0; w < 4; ++w) {
    *(f16x8*)&As[m][c8] = xa[w] + ya[w];
    {
      int sm = t >> 2, sk = (t & 3) * 8;
      *(f16x8*)&Bs[sm][sk] = *(const f16x8*)(w1t + (size_t)sm * 128 + w * 32 + sk);
    }
    __syncthreads();
    f16x8 af[2], bfr[2];
#pragma unroll
    for (int tr = 0; tr < 2; ++tr)
      af[tr] = *(const f16x8*)&As[rw * 32 + tr * 16 + lr][quad * 8];
#pragma unroll
    for (int tc = 0; tc < 2; ++tc)
      bfr[tc] = *(const f16x8*)&Bs[cw * 32 + tc * 16 + lr][quad * 8];
#pragma unroll
    for (int tr = 0; tr < 2; ++tr)
#pragma unroll
      for (int tc = 0; tc < 2; ++tc)
        acc[tr][tc] = __builtin_amdgcn_mfma_f32_16x16x32_f16(af[tr], bfr[tc], acc[tr][tc], 0, 0, 0);
    __syncthreads();
  }
  float b1v[2], w2v[2];
#pragma unroll
  for (int tc = 0; tc < 2; ++tc) {
    int col = cw * 32 + tc * 16 + lr;
    b1v[tc] = b1[col];
    w2v[tc] = w2[col];
  }
#pragma unroll
  for (int tr = 0; tr < 2; ++tr) {
#pragma unroll
    for (int r = 0; r < 4; ++r) {
      float p = 0.f;
#pragma unroll
      for (int tc = 0; tc < 2; ++tc)
        p += silu_f(acc[tr][tc][r] + b1v[tc]) * w2v[tc];
#pragma unroll
      for (int ofs = 1; ofs < 16; ofs <<= 1) p += __shfl_xor(p, ofs, 64);
      if (lr == 0) red[cw][rw * 32 + tr * 16 + quad * 4 + r] = p;
    }
  }
  __syncthreads();
  if (t < 64) {
    int e = e0b + t;
    if (e < E) {
      float fs = red[0][t] + red[1][t] + b2[0];
      int i = ijc[t][0], j = ijc[t][1];
      float dx = xyz[3 * i + 0] - xyz[3 * j + 0];
      float dy = xyz[3 * i + 1] - xyz[3 * j + 1];
      float dz = xyz[3 * i + 2] - xyz[3 * j + 2];
      float dis = sqrtf(dx * dx + dy * dy + dz * dz);  // no EPS here (matches ref)
      float sc = fs / dis;
      float fx = sc * dx, fy = sc * dy, fz = sc * dz;
      atomicAdd(out + (size_t)i * 3 + 0, fx);
      atomicAdd(out + (size_t)i * 3 + 1, fy);
      atomicAdd(out + (size_t)i * 3 + 2, fz);
      atomicAdd(out + (size_t)j * 3 + 0, -fx);
      atomicAdd(out + (size_t)j * 3 + 1, -fy);
      atomicAdd(out + (size_t)j * 3 + 2, -fz);
    }
  }
}

extern "C" void kernel_launch(void* const* d_in, const int* in_sizes, int n_in,
                              void* d_out, int out_size, void* d_ws, size_t ws_size,
                              hipStream_t stream) {
  const float* xyz    = (const float*)d_in[0];
  const int*   z      = (const int*)d_in[1];
  const int*   nbr    = (const int*)d_in[2];
  const float* embed  = (const float*)d_in[3];
  const float* msg_w1 = (const float*)d_in[4];
  const float* msg_b1 = (const float*)d_in[5];
  const float* msg_w2 = (const float*)d_in[6];
  const float* msg_b2 = (const float*)d_in[7];
  const float* dist_w = (const float*)d_in[8];
  const float* dist_b = (const float*)d_in[9];
  const float* upd_u  = (const float*)d_in[10];
  const float* upd_v  = (const float*)d_in[11];
  const float* upd_w1 = (const float*)d_in[12];
  const float* upd_b1 = (const float*)d_in[13];
  const float* upd_w2 = (const float*)d_in[14];
  const float* upd_b2 = (const float*)d_in[15];
  const float* ero_w1 = (const float*)d_in[16];
  const float* ero_b1 = (const float*)d_in[17];
  const float* ero_w2 = (const float*)d_in[18];
  const float* ero_b2 = (const float*)d_in[19];

  const int N = in_sizes[1];      // 10000
  const int E = in_sizes[2] / 2;  // 160000
  const int L = 3;

  char* ws = (char*)d_ws;
  size_t off = 0;
  auto alloc = [&](size_t bytes) -> void* {
    void* p = ws + off;
    off += (bytes + 255) & ~(size_t)255;
    return p;
  };
  float* unit_s = (float*)alloc((size_t)E * 3 * 4);
  f16*   rbf_h  = (f16*)alloc((size_t)E * 32 * 2);
  int2*  ij_s   = (int2*)alloc((size_t)E * 8);
  int*   order  = (int*)alloc((size_t)E * 4);
  float* s      = (float*)alloc((size_t)N * 128 * 4);
  f16*   s_h    = (f16*)alloc((size_t)N * 128 * 2);
  float* vA     = (float*)alloc((size_t)N * 384 * 4);
  f16*   vhA    = (f16*)alloc((size_t)N * 384 * 2);
  f16*   phi_h  = (f16*)alloc((size_t)N * 384 * 2);
  f16*   w1t    = (f16*)alloc((size_t)64 * 128 * 2);
  f16*   dwf    = (f16*)alloc((size_t)3 * 24 * 64 * 8 * 2);
  int*   histx  = (int*)alloc((size_t)(N + 1) * 4);
  int*   startp = (int*)alloc((size_t)(N + 1) * 4);
  int*   cursor = (int*)alloc((size_t)N * 4);
  float* u_v    = (float*)alloc((size_t)N * 384 * 4);
  float* v_v    = (float*)alloc((size_t)N * 384 * 4);
  float* sp     = (float*)alloc((size_t)N * 384 * 4);
  f16*   sstk_h = (f16*)alloc((size_t)N * 256 * 2);
  f16*   h_h    = (f16*)alloc((size_t)N * 128 * 2);

  auto cdiv = [](int a, int b) { return (a + b - 1) / b; };

  // ---- setup: deterministic CSR + weight pre-pack ----
  hipMemsetAsync(vA, 0, (size_t)N * 384 * 4, stream);
  hipMemsetAsync(vhA, 0, (size_t)N * 384 * 2, stream);
  hipMemsetAsync(histx, 0, (size_t)(N + 1) * 4, stream);
  hist_kernel<<<cdiv(E, 256), 256, 0, stream>>>(nbr, histx, E);
  scan_kernel<<<1, 1024, 0, stream>>>(histx, startp, cursor, N);
  scatter_id_kernel<<<cdiv(E, 256), 256, 0, stream>>>(nbr, cursor, order, E);
  segsort_kernel<<<cdiv(N, 4), 256, 0, stream>>>(order, startp, N);
  geom_fill_kernel<<<cdiv(E, 256), 256, 0, stream>>>(
      order, nbr, xyz, ij_s, unit_s, rbf_h, E);
  embed_kernel<<<cdiv(N * 128, 256), 256, 0, stream>>>(z, embed, s, s_h, N);
  w1t_kernel<<<cdiv(64 * 128, 256), 256, 0, stream>>>(ero_w1, w1t);
  dwfrag_kernel<<<cdiv(3 * 24 * 64 * 8, 256), 256, 0, stream>>>(dist_w, dist_b, dwf);

  for (int l = 0; l < L; ++l) {
    // phi = silu(s @ msg_w1 + b1) @ msg_w2 + b2  -> f16 (A read from f16 mirror)
    gemm_kernel<true, 1, true><<<dim3(cdiv(N, 64), 2), 256, 0, stream>>>(
        s_h, msg_w1 + (size_t)l * 128 * 128, msg_b1 + (size_t)l * 128, nullptr, h_h, N, 128, 128);
    gemm_kernel<false, 1, true><<<dim3(cdiv(N, 64), 6), 256, 0, stream>>>(
        h_h, msg_w2 + (size_t)l * 128 * 384, msg_b2 + (size_t)l * 384, nullptr, phi_h, N, 384, 128);
    // MFMA-ws message; atomic flush into s / v (in place)
    message_kernel<<<cdiv(E, MEPB), 384, 0, stream>>>(
        ij_s, unit_s, rbf_h, dwf + (size_t)l * 24 * 64 * 8,
        phi_h, vhA, s, vA, E);
    // update block
    gemm_dual_kernel<<<dim3(cdiv(N * 3, 64), 2), 256, 0, stream>>>(
        vA, upd_u + (size_t)l * 128 * 128, upd_v + (size_t)l * 128 * 128,
        u_v, v_v, N * 3, 128, 128);
    stack_kernel<<<cdiv(N * 128, 256), 256, 0, stream>>>(s, v_v, sstk_h, N);
    gemm_kernel<true, 1, true><<<dim3(cdiv(N, 64), 2), 256, 0, stream>>>(
        sstk_h, upd_w1 + (size_t)l * 256 * 128, upd_b1 + (size_t)l * 128, nullptr, h_h, N, 128, 256);
    gemm_kernel<false, 0, true><<<dim3(cdiv(N, 64), 6), 256, 0, stream>>>(
        h_h, upd_w2 + (size_t)l * 128 * 384, upd_b2 + (size_t)l * 384, nullptr, sp, N, 384, 128);
    apply_kernel<<<cdiv(N * 128, 256), 256, 0, stream>>>(
        s, s_h, vA, vhA, u_v, v_v, sp, N);
  }

  // fused f16 MFMA readout (unsorted edges, register-prefetched gathers)
  hipMemsetAsync(d_out, 0, (size_t)out_size * 4, stream);
  readout_gemm_kernel<<<cdiv(E, 64), 256, 0, stream>>>(
      nbr, xyz, s_h, w1t, ero_b1, ero_w2, ero_b2, (float*)d_out, E);
}

// Round 10
// 834.302 us; speedup vs baseline: 2.0761x; 1.0905x over previous
//
#include <hip/hip_runtime.h>
#include <math.h>

#define EPS_F 1e-15f
#define NRBF 20
#define CUTOFF_F 5.0f
#define PI_F 3.14159265358979323846f

typedef unsigned short u16;
typedef _Float16 f16;
typedef f16 f16x8 __attribute__((ext_vector_type(8)));
typedef f16 f16x4 __attribute__((ext_vector_type(4)));
typedef f16 f16x2 __attribute__((ext_vector_type(2)));
typedef float floatx4 __attribute__((ext_vector_type(4)));

__device__ __forceinline__ float silu_f(float x) { return x / (1.0f + expf(-x)); }

// ---------------- counting sort: histogram + scan ----------------
__global__ __launch_bounds__(256) void hist_kernel(
    const int* __restrict__ nbr, int* __restrict__ hist, int E)
{
  int e = blockIdx.x * 256 + threadIdx.x;
  if (e >= E) return;
  atomicAdd(hist + nbr[2 * e], 1);
}

// single-block exclusive scan, wave-shfl based (few barriers)
__global__ __launch_bounds__(1024) void scan_kernel(
    const int* __restrict__ hist, int* __restrict__ start,
    int* __restrict__ cursor, int N)
{
  __shared__ int wsum[16];
  __shared__ int carry_s;
  int tid = threadIdx.x;
  int lane = tid & 63, wid = tid >> 6;
  if (tid == 0) carry_s = 0;
  __syncthreads();
  for (int base = 0; base < N; base += 1024) {
    int x = (base + tid < N) ? hist[base + tid] : 0;
    int v = x;
#pragma unroll
    for (int o = 1; o < 64; o <<= 1) {
      int t2 = __shfl_up(v, o, 64);
      if (lane >= o) v += t2;
    }
    if (lane == 63) wsum[wid] = v;
    __syncthreads();
    if (tid < 16) {
      int w = wsum[tid];
#pragma unroll
      for (int o = 1; o < 16; o <<= 1) {
        int t2 = __shfl_up(w, o, 64);
        if (tid >= o) w += t2;
      }
      wsum[tid] = w;
    }
    __syncthreads();
    int wbase = (wid == 0) ? 0 : wsum[wid - 1];
    int incl = v + wbase;
    int carry = carry_s;
    if (base + tid < N) {
      int ex = carry + incl - x;
      start[base + tid] = ex;
      cursor[base + tid] = ex;
    }
    __syncthreads();
    if (tid == 1023) carry_s = carry + incl;
    __syncthreads();
  }
  if (tid == 0) start[N] = carry_s;
}

// ---------------- scatter edge IDs ----------------
__global__ __launch_bounds__(256) void scatter_id_kernel(
    const int* __restrict__ nbr, int* __restrict__ cursor,
    int* __restrict__ order, int E)
{
  int e = blockIdx.x * 256 + threadIdx.x;
  if (e >= E) return;
  int pos = atomicAdd(cursor + nbr[2 * e], 1);
  order[pos] = e;
}

// ---------------- canonicalize: wave rank-sort of each atom's segment ----------------
__global__ __launch_bounds__(256) void segsort_kernel(
    int* __restrict__ order, const int* __restrict__ start, int N)
{
  int wi = blockIdx.x * 4 + (threadIdx.x >> 6);
  int lane = threadIdx.x & 63;
  if (wi >= N) return;
  int s0 = start[wi], s1 = start[wi + 1];
  int len = s1 - s0;
  if (len <= 1) return;
  if (len <= 64) {
    int id = (lane < len) ? order[s0 + lane] : 0x7FFFFFFF;
    int rank = 0;
#pragma unroll
    for (int k = 0; k < 64; ++k) {
      int other = __shfl(id, k, 64);
      rank += (other < id) ? 1 : 0;
    }
    if (lane < len) order[s0 + rank] = id;
  } else if (lane == 0) {
    for (int a = s0 + 1; a < s1; ++a) {
      int key = order[a];
      int b = a - 1;
      while (b >= s0 && order[b] > key) { order[b + 1] = order[b]; --b; }
      order[b + 1] = key;
    }
  }
}

// ---------------- geometry gather-fill (deterministic) ----------------
// rbf_h row layout (32 f16): slots 0..19 = sin(k_n d)/d * env   (env pre-folded)
//                            slot  20    = env
//                            slots 21..31 = 0
__global__ __launch_bounds__(256) void geom_fill_kernel(
    const int* __restrict__ order, const int* __restrict__ nbr,
    const float* __restrict__ xyz, int2* __restrict__ ij_s,
    float* __restrict__ unit_s, f16* __restrict__ rbf_h, int E)
{
  int p = blockIdx.x * 256 + threadIdx.x;
  if (p >= E) return;
  int e = order[p];
  int i = nbr[2 * e], j = nbr[2 * e + 1];
  float dx = xyz[3 * j + 0] - xyz[3 * i + 0];
  float dy = xyz[3 * j + 1] - xyz[3 * i + 1];
  float dz = xyz[3 * j + 2] - xyz[3 * i + 2];
  float d2 = dx * dx + dy * dy + dz * dz + 3.0f * EPS_F;  // ref adds EPS per comp
  float d = sqrtf(d2);
  float inv_d = 1.0f / d;
  ij_s[p] = make_int2(i, j);
  unit_s[3 * p + 0] = dx * inv_d;
  unit_s[3 * p + 1] = dy * inv_d;
  unit_s[3 * p + 2] = dz * inv_d;
  float x = d * (PI_F / CUTOFF_F);
  float s1, c1;
  __sincosf(x, &s1, &c1);
  float envv = (d < CUTOFF_F) ? 0.5f * (c1 + 1.0f) : 0.0f;
  f16 tmp[32];
  float two_c = 2.0f * c1;
  float env_inv_d = envv * inv_d;
  float sp = 0.0f, sn = s1;           // Chebyshev recurrence for sin(n*x)
  tmp[0] = (f16)(sn * env_inv_d);
#pragma unroll
  for (int n = 1; n < NRBF; ++n) {
    float nx = two_c * sn - sp;
    sp = sn; sn = nx;
    tmp[n] = (f16)(sn * env_inv_d);
  }
  tmp[NRBF] = (f16)envv;
#pragma unroll
  for (int n = NRBF + 1; n < 32; ++n) tmp[n] = (f16)0.0f;
#pragma unroll
  for (int g = 0; g < 4; ++g)
    *(f16x8*)(rbf_h + (size_t)p * 32 + g * 8) = *(f16x8*)&tmp[g * 8];
}

// ---------------- pre-pack dwx = [dist_w; dist_b; 0] into MFMA B-fragment order ----------------
__global__ __launch_bounds__(256) void dwfrag_kernel(
    const float* __restrict__ dw, const float* __restrict__ db,
    f16* __restrict__ dwf)
{
  int idx = blockIdx.x * 256 + threadIdx.x;
  if (idx >= 3 * 24 * 64 * 8) return;
  int q = idx & 7;
  int lane = (idx >> 3) & 63;
  int ct = (idx >> 9) % 24;
  int l = idx / (24 * 64 * 8);
  int k = (lane >> 4) * 8 + q;
  int col = ct * 16 + (lane & 15);
  float val = 0.f;
  if (k < NRBF) val = dw[(size_t)l * NRBF * 384 + (size_t)k * 384 + col];
  else if (k == NRBF) val = db[(size_t)l * 384 + col];
  dwf[idx] = (f16)val;
}

// ---------------- s = embed[z] (fp32 + f16 mirror) ----------------
__global__ __launch_bounds__(256) void embed_kernel(
    const int* __restrict__ z, const float* __restrict__ embed,
    float* __restrict__ s, f16* __restrict__ s_h, int N)
{
  int idx = blockIdx.x * 256 + threadIdx.x;
  if (idx >= N * 128) return;
  int n = idx >> 7, f = idx & 127;
  float x = embed[z[n] * 128 + f];
  s[idx] = x;
  s_h[idx] = (f16)x;
}

__global__ __launch_bounds__(256) void w1t_kernel(
    const float* __restrict__ w1, f16* __restrict__ w1t)
{
  int idx = blockIdx.x * 256 + threadIdx.x;
  if (idx >= 64 * 128) return;
  int n = idx >> 7, k = idx & 127;
  w1t[idx] = (f16)w1[(size_t)k * 64 + n];
}

// ---------------- FUSED MLP: out = silu(A @ W1 + b1) @ W2 + b2 ----------------
// A: f16 (M x K1). W1: fp32 (K1 x 128). W2: fp32 (128 x 384).
// Stage 1 keeps h (64x128 per block) in LDS as f16 - bit-identical to the
// old two-kernel path (which round-tripped h as f16 through HBM), saving
// one launch + ~5MB traffic per layer per chain.
// OUT: 0 = fp32 out, 1 = f16 out.
template <int K1, int OUT>
__global__ __launch_bounds__(256) void mlp_kernel(
    const f16* __restrict__ A, const float* __restrict__ W1,
    const float* __restrict__ b1, const float* __restrict__ W2,
    const float* __restrict__ b2, void* __restrict__ Cout, int M)
{
  __shared__ f16 As[64][40];
  __shared__ f16 Bs1[128][40];   // stage1 B (128 cols); stage2 reuses first 64 rows
  __shared__ f16 hs[64][136];    // h, padded stride
  int t = threadIdx.x;
  int wave = t >> 6, lane = t & 63;
  int lr = lane & 15, quad = lane >> 4;
  int row0 = blockIdx.x * 64;

  // ---- stage 1: h = silu(A @ W1 + b1), block computes 64 x 128 ----
  // wave owns cols [wave*32, wave*32+32): 2 col-tiles x 4 row-tiles
  floatx4 acc_h[4][2] = {};
  for (int k0 = 0; k0 < K1; k0 += 32) {
    {
      int sm = t >> 2, sk = (t & 3) * 8;
      f16x8 av;
      if (row0 + sm < M) av = *(const f16x8*)(A + (size_t)(row0 + sm) * K1 + k0 + sk);
      else { for (int q = 0; q < 8; ++q) av[q] = (f16)0.0f; }
      *(f16x8*)&As[sm][sk] = av;
    }
#pragma unroll
    for (int u0 = 0; u0 < 4; ++u0) {
      int u = t + u0 * 256;          // 0..1023
      int k = u >> 5;                // 0..31
      int c4 = (u & 31) * 4;         // 0..124
      float4 wv = *(const float4*)(W1 + (size_t)(k0 + k) * 128 + c4);
      Bs1[c4 + 0][k] = (f16)wv.x;
      Bs1[c4 + 1][k] = (f16)wv.y;
      Bs1[c4 + 2][k] = (f16)wv.z;
      Bs1[c4 + 3][k] = (f16)wv.w;
    }
    __syncthreads();
    f16x8 af[4], bfr[2];
#pragma unroll
    for (int tr = 0; tr < 4; ++tr)
      af[tr] = *(const f16x8*)&As[tr * 16 + lr][quad * 8];
#pragma unroll
    for (int tc = 0; tc < 2; ++tc)
      bfr[tc] = *(const f16x8*)&Bs1[wave * 32 + tc * 16 + lr][quad * 8];
#pragma unroll
    for (int tr = 0; tr < 4; ++tr)
#pragma unroll
      for (int tc = 0; tc < 2; ++tc)
        acc_h[tr][tc] = __builtin_amdgcn_mfma_f32_16x16x32_f16(af[tr], bfr[tc], acc_h[tr][tc], 0, 0, 0);
    __syncthreads();
  }
  // write h to LDS with bias + silu (f16: same rounding as old h_h path)
#pragma unroll
  for (int tc = 0; tc < 2; ++tc) {
    int col = wave * 32 + tc * 16 + lr;
    float bb = b1[col];
#pragma unroll
    for (int tr = 0; tr < 4; ++tr) {
#pragma unroll
      for (int r = 0; r < 4; ++r) {
        int row = tr * 16 + quad * 4 + r;
        hs[row][col] = (f16)silu_f(acc_h[tr][tc][r] + bb);
      }
    }
  }
  __syncthreads();

  // ---- stage 2: out = h @ W2 + b2, 6 column chunks of 64 ----
  int rw = wave & 1, cw = wave >> 1;
  for (int chunk = 0; chunk < 6; ++chunk) {
    int c0 = chunk * 64;
    floatx4 acc[2][2] = {};
    for (int k0 = 0; k0 < 128; k0 += 32) {
#pragma unroll
      for (int u0 = 0; u0 < 2; ++u0) {
        int u = t + u0 * 256;
        int k = u >> 4, n4 = (u & 15) * 4;
        float4 wv = *(const float4*)(W2 + (size_t)(k0 + k) * 384 + c0 + n4);
        Bs1[n4 + 0][k] = (f16)wv.x;
        Bs1[n4 + 1][k] = (f16)wv.y;
        Bs1[n4 + 2][k] = (f16)wv.z;
        Bs1[n4 + 3][k] = (f16)wv.w;
      }
      __syncthreads();
      f16x8 af[2], bfr[2];
#pragma unroll
      for (int tr = 0; tr < 2; ++tr)
        af[tr] = *(const f16x8*)&hs[rw * 32 + tr * 16 + lr][k0 + quad * 8];
#pragma unroll
      for (int tc = 0; tc < 2; ++tc)
        bfr[tc] = *(const f16x8*)&Bs1[cw * 32 + tc * 16 + lr][quad * 8];
#pragma unroll
      for (int tr = 0; tr < 2; ++tr)
#pragma unroll
        for (int tc = 0; tc < 2; ++tc)
          acc[tr][tc] = __builtin_amdgcn_mfma_f32_16x16x32_f16(af[tr], bfr[tc], acc[tr][tc], 0, 0, 0);
      __syncthreads();
    }
#pragma unroll
    for (int tc = 0; tc < 2; ++tc) {
      int col = c0 + cw * 32 + tc * 16 + lr;
      float bb = b2[col];
#pragma unroll
      for (int tr = 0; tr < 2; ++tr) {
#pragma unroll
        for (int r = 0; r < 4; ++r) {
          int row = row0 + rw * 32 + tr * 16 + quad * 4 + r;
          if (row < M) {
            float x = acc[tr][tc][r] + bb;
            size_t o = (size_t)row * 384 + col;
            if (OUT == 0) ((float*)Cout)[o] = x;
            else          ((f16*)Cout)[o] = (f16)x;
          }
        }
      }
    }
  }
}

// ---------------- dual-weight f16 MFMA GEMM: C1 = A@W1, C2 = A@W2 (fp32 A/out) ----------------
__global__ __launch_bounds__(256) void gemm_dual_kernel(
    const float* __restrict__ A, const float* __restrict__ W1,
    const float* __restrict__ W2, float* __restrict__ C1, float* __restrict__ C2,
    int M, int N, int K)
{
  __shared__ f16 As[64][40];
  __shared__ f16 Bs1[64][40];
  __shared__ f16 Bs2[64][40];
  int t = threadIdx.x;
  int wave = t >> 6, lane = t & 63;
  int rw = wave & 1, cw = wave >> 1;
  int lr = lane & 15, quad = lane >> 4;
  int row0 = blockIdx.x * 64, col0 = blockIdx.y * 64;
  floatx4 acc1[2][2] = {};
  floatx4 acc2[2][2] = {};
  for (int k0 = 0; k0 < K; k0 += 32) {
#pragma unroll
    for (int u0 = 0; u0 < 2; ++u0) {
      int u = t + u0 * 256;
      int m = u >> 3, c4 = (u & 7) * 4;
      float4 av = make_float4(0.f, 0.f, 0.f, 0.f);
      if (row0 + m < M) av = *(const float4*)(A + (size_t)(row0 + m) * K + k0 + c4);
      f16x4 hv;
      hv[0] = (f16)av.x; hv[1] = (f16)av.y; hv[2] = (f16)av.z; hv[3] = (f16)av.w;
      *(f16x4*)&As[m][c4] = hv;
    }
#pragma unroll
    for (int u0 = 0; u0 < 2; ++u0) {
      int u = t + u0 * 256;
      int k = u >> 4, n4 = (u & 15) * 4;
      float4 wv = *(const float4*)(W1 + (size_t)(k0 + k) * N + col0 + n4);
      Bs1[n4 + 0][k] = (f16)wv.x;
      Bs1[n4 + 1][k] = (f16)wv.y;
      Bs1[n4 + 2][k] = (f16)wv.z;
      Bs1[n4 + 3][k] = (f16)wv.w;
      float4 xv = *(const float4*)(W2 + (size_t)(k0 + k) * N + col0 + n4);
      Bs2[n4 + 0][k] = (f16)xv.x;
      Bs2[n4 + 1][k] = (f16)xv.y;
      Bs2[n4 + 2][k] = (f16)xv.z;
      Bs2[n4 + 3][k] = (f16)xv.w;
    }
    __syncthreads();
    f16x8 af[2], b1[2], b2[2];
#pragma unroll
    for (int tr = 0; tr < 2; ++tr)
      af[tr] = *(const f16x8*)&As[rw * 32 + tr * 16 + lr][quad * 8];
#pragma unroll
    for (int tc = 0; tc < 2; ++tc) {
      b1[tc] = *(const f16x8*)&Bs1[cw * 32 + tc * 16 + lr][quad * 8];
      b2[tc] = *(const f16x8*)&Bs2[cw * 32 + tc * 16 + lr][quad * 8];
    }
#pragma unroll
    for (int tr = 0; tr < 2; ++tr)
#pragma unroll
      for (int tc = 0; tc < 2; ++tc) {
        acc1[tr][tc] = __builtin_amdgcn_mfma_f32_16x16x32_f16(af[tr], b1[tc], acc1[tr][tc], 0, 0, 0);
        acc2[tr][tc] = __builtin_amdgcn_mfma_f32_16x16x32_f16(af[tr], b2[tc], acc2[tr][tc], 0, 0, 0);
      }
    __syncthreads();
  }
#pragma unroll
  for (int tc = 0; tc < 2; ++tc) {
    int col = col0 + cw * 32 + tc * 16 + lr;
#pragma unroll
    for (int tr = 0; tr < 2; ++tr) {
#pragma unroll
      for (int r = 0; r < 4; ++r) {
        int row = row0 + rw * 32 + tr * 16 + quad * 4 + r;
        if (row < M) {
          C1[(size_t)row * N + col] = acc1[tr][tc][r];
          C2[(size_t)row * N + col] = acc2[tr][tc][r];
        }
      }
    }
  }
}

// ---------------- MFMA-ws message kernel (r4 version - best measured: 90us) ----------------
// Phase A: ws_tile[32][384] = rbfA @ dwx via 48 MFMAs.
// Phase B: gather loop with 8-deep register pipeline (named slots).
// r5-r9 restructurings (3-stage pipeline, 12-wave, two-pass LDS, async
// global_load_lds staging) all measured WORSE (112-427us). Reverted.
#define MEPB 32
__global__ __launch_bounds__(384, 4) void message_kernel(
    const int2* __restrict__ ij_s, const float* __restrict__ unit_s,
    const f16* __restrict__ rbf_h, const f16* __restrict__ dwf,
    const f16* __restrict__ phi_h, const f16* __restrict__ vh,
    float* __restrict__ s, float* __restrict__ v, int E)
{
  __shared__ f16 rbfA[MEPB][40];
  __shared__ f16 wsT[384][38];
  __shared__ int2 ijL[MEPB];
  __shared__ float unitL[MEPB * 3];
  int t = threadIdx.x;
  int wave = t >> 6, lane = t & 63;
  int e_lo = blockIdx.x * MEPB;
  if (e_lo >= E) return;
  int e_hi = (e_lo + MEPB < E) ? e_lo + MEPB : E;
  int cnt = e_hi - e_lo;

  // ---- B fragments: 4 col-tiles per wave, from frag-ordered dwf ----
  f16x8 bf[4];
#pragma unroll
  for (int i = 0; i < 4; ++i) {
    int ct = wave * 4 + i;
    bf[i] = *(const f16x8*)(dwf + ((size_t)ct * 64 + lane) * 8);
  }
  // ---- stage rbf rows / ij / unit ----
  if (t < MEPB * 4) {
    int r = t >> 2, c8 = (t & 3) * 8;
    f16x8 rv;
    if (e_lo + r < E) rv = *(const f16x8*)(rbf_h + (size_t)(e_lo + r) * 32 + c8);
    else { for (int q = 0; q < 8; ++q) rv[q] = (f16)0.0f; }
    *(f16x8*)&rbfA[r][c8] = rv;
  }
  if (t < cnt) ijL[t] = ij_s[e_lo + t];
  if (t < cnt * 3) unitL[t] = unit_s[(size_t)e_lo * 3 + t];
  __syncthreads();

  // ---- MFMA: 2 row-tiles x 4 col-tiles per wave ----
  int lr = lane & 15, quad = lane >> 4;
  f16x8 af[2];
#pragma unroll
  for (int tr = 0; tr < 2; ++tr)
    af[tr] = *(const f16x8*)&rbfA[tr * 16 + lr][quad * 8];
  floatx4 acc[2][4] = {};
#pragma unroll
  for (int tr = 0; tr < 2; ++tr)
#pragma unroll
    for (int i = 0; i < 4; ++i)
      acc[tr][i] = __builtin_amdgcn_mfma_f32_16x16x32_f16(af[tr], bf[i], acc[tr][i], 0, 0, 0);
  // C/D layout: col = lane&15 (within tile), row = quad*4 + r  -> write transposed
#pragma unroll
  for (int tr = 0; tr < 2; ++tr)
#pragma unroll
    for (int i = 0; i < 4; ++i) {
      int col = (wave * 4 + i) * 16 + lr;
      int er = tr * 16 + quad * 4;
      f16x2 lo2, hi2;
      lo2[0] = (f16)acc[tr][i][0]; lo2[1] = (f16)acc[tr][i][1];
      hi2[0] = (f16)acc[tr][i][2]; hi2[1] = (f16)acc[tr][i][3];
      *(f16x2*)&wsT[col][er]     = lo2;
      *(f16x2*)&wsT[col][er + 2] = hi2;
    }
  __syncthreads();

  // ---- Phase B: gather + segment flush, 8-deep pipeline ----
  int g = t >> 7, f = t & 127;
  float a0 = 0.f, a1 = 0.f, a2 = 0.f;
  int prev_i = -1;
  f16 ph_0 = (f16)0.f, ph_1 = (f16)0.f, ph_2 = (f16)0.f, ph_3 = (f16)0.f;
  f16 ph_4 = (f16)0.f, ph_5 = (f16)0.f, ph_6 = (f16)0.f, ph_7 = (f16)0.f;
  f16 vj0_0 = (f16)0.f, vj1_0 = (f16)0.f, vj2_0 = (f16)0.f;
  f16 vj0_1 = (f16)0.f, vj1_1 = (f16)0.f, vj2_1 = (f16)0.f;
  f16 vj0_2 = (f16)0.f, vj1_2 = (f16)0.f, vj2_2 = (f16)0.f;
  f16 vj0_3 = (f16)0.f, vj1_3 = (f16)0.f, vj2_3 = (f16)0.f;
  f16 vj0_4 = (f16)0.f, vj1_4 = (f16)0.f, vj2_4 = (f16)0.f;
  f16 vj0_5 = (f16)0.f, vj1_5 = (f16)0.f, vj2_5 = (f16)0.f;
  f16 vj0_6 = (f16)0.f, vj1_6 = (f16)0.f, vj2_6 = (f16)0.f;
  f16 vj0_7 = (f16)0.f, vj1_7 = (f16)0.f, vj2_7 = (f16)0.f;

#define MK_LOAD(S, RR) do { int rv_ = (RR); if (rv_ < cnt) {                  \
    int jj_ = ijL[rv_].y;                                                      \
    ph_##S = phi_h[(size_t)jj_ * 384 + t];                                     \
    if (g == 0) { const f16* vp_ = vh + (size_t)jj_ * 384 + f;                 \
      vj0_##S = vp_[0]; vj1_##S = vp_[128]; vj2_##S = vp_[256]; }              \
  } } while (0)

#define MK_PROC(S, RR) do { int rv_ = (RR); if (rv_ < cnt) {                   \
    int ix_ = ijL[rv_].x;                                                      \
    if (ix_ != prev_i) {                                                       \
      if (prev_i >= 0) {                                                       \
        if (g == 1) atomicAdd(s + (size_t)prev_i * 128 + f, a0);               \
        else { float* vb_ = v + (size_t)prev_i * 384 + f;                      \
          atomicAdd(vb_, a0); atomicAdd(vb_ + 128, a1); atomicAdd(vb_ + 256, a2); } \
        a0 = a1 = a2 = 0.f; }                                                  \
      prev_i = ix_; }                                                          \
    float ws_ = (float)wsT[t][rv_];                                            \
    float inv_ = (float)ph_##S * ws_;                                          \
    if (g == 0) { a0 = fmaf(inv_, (float)vj0_##S, a0);                         \
                  a1 = fmaf(inv_, (float)vj1_##S, a1);                         \
                  a2 = fmaf(inv_, (float)vj2_##S, a2); }                       \
    else if (g == 1) { a0 += inv_; }                                           \
    else { a0 = fmaf(inv_, unitL[3 * rv_ + 0], a0);                            \
           a1 = fmaf(inv_, unitL[3 * rv_ + 1], a1);                            \
           a2 = fmaf(inv_, unitL[3 * rv_ + 2], a2); }                          \
  } } while (0)

  MK_LOAD(0, 0); MK_LOAD(1, 1); MK_LOAD(2, 2); MK_LOAD(3, 3);
  MK_LOAD(4, 4); MK_LOAD(5, 5); MK_LOAD(6, 6); MK_LOAD(7, 7);
  for (int r = 0; r < cnt; r += 8) {
    MK_PROC(0, r);     MK_LOAD(0, r + 8);
    MK_PROC(1, r + 1); MK_LOAD(1, r + 9);
    MK_PROC(2, r + 2); MK_LOAD(2, r + 10);
    MK_PROC(3, r + 3); MK_LOAD(3, r + 11);
    MK_PROC(4, r + 4); MK_LOAD(4, r + 12);
    MK_PROC(5, r + 5); MK_LOAD(5, r + 13);
    MK_PROC(6, r + 6); MK_LOAD(6, r + 14);
    MK_PROC(7, r + 7); MK_LOAD(7, r + 15);
  }
#undef MK_LOAD
#undef MK_PROC
  // ---- final flush ----
  if (prev_i >= 0) {
    if (g == 1) {
      atomicAdd(s + (size_t)prev_i * 128 + f, a0);
    } else {
      float* vb = v + (size_t)prev_i * 384 + f;
      atomicAdd(vb, a0);
      atomicAdd(vb + 128, a1);
      atomicAdd(vb + 256, a2);
    }
  }
}

// ---------------- s_stack = [s, ||v_v||] (f16 out) ----------------
__global__ __launch_bounds__(256) void stack_kernel(
    const float* __restrict__ s, const float* __restrict__ v_v,
    f16* __restrict__ s_stack, int N)
{
  int idx = blockIdx.x * 256 + threadIdx.x;
  if (idx >= N * 128) return;
  int n = idx >> 7, g = idx & 127;
  float a = v_v[(size_t)n * 384 + g];
  float b = v_v[(size_t)n * 384 + 128 + g];
  float c = v_v[(size_t)n * 384 + 256 + g];
  s_stack[(size_t)n * 256 + g] = (f16)s[idx];
  s_stack[(size_t)n * 256 + 128 + g] = (f16)sqrtf(a * a + b * b + c * c + EPS_F);
}

// ---------------- gated update of s, v (+ f16 mirrors for next-layer reads) ----------------
__global__ __launch_bounds__(256) void apply_kernel(
    float* __restrict__ s, f16* __restrict__ s_h,
    float* __restrict__ v, f16* __restrict__ v_h,
    const float* __restrict__ u_v, const float* __restrict__ v_v,
    const float* __restrict__ sp, int N)
{
  int idx = blockIdx.x * 256 + threadIdx.x;
  if (idx >= N * 128) return;
  int n = idx >> 7, g = idx & 127;
  float sp0 = sp[(size_t)n * 384 + g];
  float sp1 = sp[(size_t)n * 384 + 128 + g];
  float sp2 = sp[(size_t)n * 384 + 256 + g];
  float dot = 0.f;
#pragma unroll
  for (int c = 0; c < 3; ++c) {
    size_t o = (size_t)n * 384 + c * 128 + g;
    float uv = u_v[o];
    float vn = fmaf(uv, sp0, v[o]);
    v[o] = vn;
    v_h[o] = (f16)vn;
    dot = fmaf(uv, v_v[o], dot);
  }
  float sn = s[idx] + dot * sp1 + sp2;
  s[idx] = sn;
  s_h[idx] = (f16)sn;
}

// ---------------- fused f16 MFMA readout (unsorted edges; register-prefetched gathers) ----------------
__global__ __launch_bounds__(256) void readout_gemm_kernel(
    const int* __restrict__ nbr, const float* __restrict__ xyz,
    const f16* __restrict__ s_h, const f16* __restrict__ w1t,
    const float* __restrict__ b1, const float* __restrict__ w2,
    const float* __restrict__ b2, float* __restrict__ out, int E)
{
  __shared__ f16 As[64][40];
  __shared__ f16 Bs[64][40];
  __shared__ float red[2][64];
  __shared__ int ijc[64][2];
  int t = threadIdx.x;
  int wave = t >> 6, lane = t & 63;
  int rw = wave & 1, cw = wave >> 1;
  int lr = lane & 15, quad = lane >> 4;
  int e0b = blockIdx.x * 64;
  if (t < 64) {
    int e = e0b + t;
    if (e < E) { ijc[t][0] = nbr[2 * e]; ijc[t][1] = nbr[2 * e + 1]; }
    else { ijc[t][0] = 0; ijc[t][1] = 0; }
  }
  __syncthreads();
  int m = t >> 2;             // one row (edge) per thread
  int c8 = (t & 3) * 8;       // 8 features within 32-k window
  int im = ijc[m][0], jm = ijc[m][1];
  bool okm = (e0b + m) < E;
  // prefetch all 8 row-segments (4 windows x i/j) - independent loads in flight
  f16x8 xa[4], ya[4];
  if (okm) {
#pragma unroll
    for (int w = 0; w < 4; ++w) {
      xa[w] = *(const f16x8*)(s_h + (size_t)im * 128 + w * 32 + c8);
      ya[w] = *(const f16x8*)(s_h + (size_t)jm * 128 + w * 32 + c8);
    }
  } else {
#pragma unroll
    for (int w = 0; w < 4; ++w)
      for (int q = 0; q < 8; ++q) { xa[w][q] = (f16)0.0f; ya[w][q] = (f16)0.0f; }
  }
  floatx4 acc[2][2] = {};
#pragma unroll
  for (int w = 0; w < 4; ++w) {
    *(f16x8*)&As[m][c8] = xa[w] + ya[w];
    {
      int sm = t >> 2, sk = (t & 3) * 8;
      *(f16x8*)&Bs[sm][sk] = *(const f16x8*)(w1t + (size_t)sm * 128 + w * 32 + sk);
    }
    __syncthreads();
    f16x8 af[2], bfr[2];
#pragma unroll
    for (int tr = 0; tr < 2; ++tr)
      af[tr] = *(const f16x8*)&As[rw * 32 + tr * 16 + lr][quad * 8];
#pragma unroll
    for (int tc = 0; tc < 2; ++tc)
      bfr[tc] = *(const f16x8*)&Bs[cw * 32 + tc * 16 + lr][quad * 8];
#pragma unroll
    for (int tr = 0; tr < 2; ++tr)
#pragma unroll
      for (int tc = 0; tc < 2; ++tc)
        acc[tr][tc] = __builtin_amdgcn_mfma_f32_16x16x32_f16(af[tr], bfr[tc], acc[tr][tc], 0, 0, 0);
    __syncthreads();
  }
  float b1v[2], w2v[2];
#pragma unroll
  for (int tc = 0; tc < 2; ++tc) {
    int col = cw * 32 + tc * 16 + lr;
    b1v[tc] = b1[col];
    w2v[tc] = w2[col];
  }
#pragma unroll
  for (int tr = 0; tr < 2; ++tr) {
#pragma unroll
    for (int r = 0; r < 4; ++r) {
      float p = 0.f;
#pragma unroll
      for (int tc = 0; tc < 2; ++tc)
        p += silu_f(acc[tr][tc][r] + b1v[tc]) * w2v[tc];
#pragma unroll
      for (int ofs = 1; ofs < 16; ofs <<= 1) p += __shfl_xor(p, ofs, 64);
      if (lr == 0) red[cw][rw * 32 + tr * 16 + quad * 4 + r] = p;
    }
  }
  __syncthreads();
  if (t < 64) {
    int e = e0b + t;
    if (e < E) {
      float fs = red[0][t] + red[1][t] + b2[0];
      int i = ijc[t][0], j = ijc[t][1];
      float dx = xyz[3 * i + 0] - xyz[3 * j + 0];
      float dy = xyz[3 * i + 1] - xyz[3 * j + 1];
      float dz = xyz[3 * i + 2] - xyz[3 * j + 2];
      float dis = sqrtf(dx * dx + dy * dy + dz * dz);  // no EPS here (matches ref)
      float sc = fs / dis;
      float fx = sc * dx, fy = sc * dy, fz = sc * dz;
      atomicAdd(out + (size_t)i * 3 + 0, fx);
      atomicAdd(out + (size_t)i * 3 + 1, fy);
      atomicAdd(out + (size_t)i * 3 + 2, fz);
      atomicAdd(out + (size_t)j * 3 + 0, -fx);
      atomicAdd(out + (size_t)j * 3 + 1, -fy);
      atomicAdd(out + (size_t)j * 3 + 2, -fz);
    }
  }
}

extern "C" void kernel_launch(void* const* d_in, const int* in_sizes, int n_in,
                              void* d_out, int out_size, void* d_ws, size_t ws_size,
                              hipStream_t stream) {
  const float* xyz    = (const float*)d_in[0];
  const int*   z      = (const int*)d_in[1];
  const int*   nbr    = (const int*)d_in[2];
  const float* embed  = (const float*)d_in[3];
  const float* msg_w1 = (const float*)d_in[4];
  const float* msg_b1 = (const float*)d_in[5];
  const float* msg_w2 = (const float*)d_in[6];
  const float* msg_b2 = (const float*)d_in[7];
  const float* dist_w = (const float*)d_in[8];
  const float* dist_b = (const float*)d_in[9];
  const float* upd_u  = (const float*)d_in[10];
  const float* upd_v  = (const float*)d_in[11];
  const float* upd_w1 = (const float*)d_in[12];
  const float* upd_b1 = (const float*)d_in[13];
  const float* upd_w2 = (const float*)d_in[14];
  const float* upd_b2 = (const float*)d_in[15];
  const float* ero_w1 = (const float*)d_in[16];
  const float* ero_b1 = (const float*)d_in[17];
  const float* ero_w2 = (const float*)d_in[18];
  const float* ero_b2 = (const float*)d_in[19];

  const int N = in_sizes[1];      // 10000
  const int E = in_sizes[2] / 2;  // 160000
  const int L = 3;

  char* ws = (char*)d_ws;
  size_t off = 0;
  auto alloc = [&](size_t bytes) -> void* {
    void* p = ws + off;
    off += (bytes + 255) & ~(size_t)255;
    return p;
  };
  float* unit_s = (float*)alloc((size_t)E * 3 * 4);
  f16*   rbf_h  = (f16*)alloc((size_t)E * 32 * 2);
  int2*  ij_s   = (int2*)alloc((size_t)E * 8);
  int*   order  = (int*)alloc((size_t)E * 4);
  float* s      = (float*)alloc((size_t)N * 128 * 4);
  f16*   s_h    = (f16*)alloc((size_t)N * 128 * 2);
  float* vA     = (float*)alloc((size_t)N * 384 * 4);
  f16*   vhA    = (f16*)alloc((size_t)N * 384 * 2);
  f16*   phi_h  = (f16*)alloc((size_t)N * 384 * 2);
  f16*   w1t    = (f16*)alloc((size_t)64 * 128 * 2);
  f16*   dwf    = (f16*)alloc((size_t)3 * 24 * 64 * 8 * 2);
  int*   histx  = (int*)alloc((size_t)(N + 1) * 4);
  int*   startp = (int*)alloc((size_t)(N + 1) * 4);
  int*   cursor = (int*)alloc((size_t)N * 4);
  float* u_v    = (float*)alloc((size_t)N * 384 * 4);
  float* v_v    = (float*)alloc((size_t)N * 384 * 4);
  float* sp     = (float*)alloc((size_t)N * 384 * 4);
  f16*   sstk_h = (f16*)alloc((size_t)N * 256 * 2);

  auto cdiv = [](int a, int b) { return (a + b - 1) / b; };

  // ---- setup: deterministic CSR + weight pre-pack ----
  hipMemsetAsync(vA, 0, (size_t)N * 384 * 4, stream);
  hipMemsetAsync(vhA, 0, (size_t)N * 384 * 2, stream);
  hipMemsetAsync(histx, 0, (size_t)(N + 1) * 4, stream);
  hist_kernel<<<cdiv(E, 256), 256, 0, stream>>>(nbr, histx, E);
  scan_kernel<<<1, 1024, 0, stream>>>(histx, startp, cursor, N);
  scatter_id_kernel<<<cdiv(E, 256), 256, 0, stream>>>(nbr, cursor, order, E);
  segsort_kernel<<<cdiv(N, 4), 256, 0, stream>>>(order, startp, N);
  geom_fill_kernel<<<cdiv(E, 256), 256, 0, stream>>>(
      order, nbr, xyz, ij_s, unit_s, rbf_h, E);
  embed_kernel<<<cdiv(N * 128, 256), 256, 0, stream>>>(z, embed, s, s_h, N);
  w1t_kernel<<<cdiv(64 * 128, 256), 256, 0, stream>>>(ero_w1, w1t);
  dwfrag_kernel<<<cdiv(3 * 24 * 64 * 8, 256), 256, 0, stream>>>(dist_w, dist_b, dwf);

  for (int l = 0; l < L; ++l) {
    // phi = silu(s @ msg_w1 + b1) @ msg_w2 + b2  -> f16 (fused MLP, h stays in LDS)
    mlp_kernel<128, 1><<<cdiv(N, 64), 256, 0, stream>>>(
        s_h, msg_w1 + (size_t)l * 128 * 128, msg_b1 + (size_t)l * 128,
        msg_w2 + (size_t)l * 128 * 384, msg_b2 + (size_t)l * 384, phi_h, N);
    // MFMA-ws message; atomic flush into s / v (in place)
    message_kernel<<<cdiv(E, MEPB), 384, 0, stream>>>(
        ij_s, unit_s, rbf_h, dwf + (size_t)l * 24 * 64 * 8,
        phi_h, vhA, s, vA, E);
    // update block
    gemm_dual_kernel<<<dim3(cdiv(N * 3, 64), 2), 256, 0, stream>>>(
        vA, upd_u + (size_t)l * 128 * 128, upd_v + (size_t)l * 128 * 128,
        u_v, v_v, N * 3, 128, 128);
    stack_kernel<<<cdiv(N * 128, 256), 256, 0, stream>>>(s, v_v, sstk_h, N);
    // sp = silu(sstk @ upd_w1 + b1) @ upd_w2 + b2  -> fp32 (fused MLP)
    mlp_kernel<256, 0><<<cdiv(N, 64), 256, 0, stream>>>(
        sstk_h, upd_w1 + (size_t)l * 256 * 128, upd_b1 + (size_t)l * 128,
        upd_w2 + (size_t)l * 128 * 384, upd_b2 + (size_t)l * 384, sp, N);
    apply_kernel<<<cdiv(N * 128, 256), 256, 0, stream>>>(
        s, s_h, vA, vhA, u_v, v_v, sp, N);
  }

  // fused f16 MFMA readout (unsorted edges, register-prefetched gathers)
  hipMemsetAsync(d_out, 0, (size_t)out_size * 4, stream);
  readout_gemm_kernel<<<cdiv(E, 64), 256, 0, stream>>>(
      nbr, xyz, s_h, w1t, ero_b1, ero_w2, ero_b2, (float*)d_out, E);
}

// Round 11
// 716.487 us; speedup vs baseline: 2.4175x; 1.1644x over previous
//
#include <hip/hip_runtime.h>
#include <math.h>

#define EPS_F 1e-15f
#define NRBF 20
#define CUTOFF_F 5.0f
#define PI_F 3.14159265358979323846f

typedef unsigned short u16;
typedef _Float16 f16;
typedef f16 f16x8 __attribute__((ext_vector_type(8)));
typedef f16 f16x4 __attribute__((ext_vector_type(4)));
typedef f16 f16x2 __attribute__((ext_vector_type(2)));
typedef float floatx4 __attribute__((ext_vector_type(4)));

__device__ __forceinline__ float silu_f(float x) { return x / (1.0f + expf(-x)); }

// ---------------- counting sort: histogram + scan ----------------
__global__ __launch_bounds__(256) void hist_kernel(
    const int* __restrict__ nbr, int* __restrict__ hist, int E)
{
  int e = blockIdx.x * 256 + threadIdx.x;
  if (e >= E) return;
  atomicAdd(hist + nbr[2 * e], 1);
}

// single-block exclusive scan, wave-shfl based (few barriers)
__global__ __launch_bounds__(1024) void scan_kernel(
    const int* __restrict__ hist, int* __restrict__ start,
    int* __restrict__ cursor, int N)
{
  __shared__ int wsum[16];
  __shared__ int carry_s;
  int tid = threadIdx.x;
  int lane = tid & 63, wid = tid >> 6;
  if (tid == 0) carry_s = 0;
  __syncthreads();
  for (int base = 0; base < N; base += 1024) {
    int x = (base + tid < N) ? hist[base + tid] : 0;
    int v = x;
#pragma unroll
    for (int o = 1; o < 64; o <<= 1) {
      int t2 = __shfl_up(v, o, 64);
      if (lane >= o) v += t2;
    }
    if (lane == 63) wsum[wid] = v;
    __syncthreads();
    if (tid < 16) {
      int w = wsum[tid];
#pragma unroll
      for (int o = 1; o < 16; o <<= 1) {
        int t2 = __shfl_up(w, o, 64);
        if (tid >= o) w += t2;
      }
      wsum[tid] = w;
    }
    __syncthreads();
    int wbase = (wid == 0) ? 0 : wsum[wid - 1];
    int incl = v + wbase;
    int carry = carry_s;
    if (base + tid < N) {
      int ex = carry + incl - x;
      start[base + tid] = ex;
      cursor[base + tid] = ex;
    }
    __syncthreads();
    if (tid == 1023) carry_s = carry + incl;
    __syncthreads();
  }
  if (tid == 0) start[N] = carry_s;
}

// ---------------- scatter edge IDs ----------------
__global__ __launch_bounds__(256) void scatter_id_kernel(
    const int* __restrict__ nbr, int* __restrict__ cursor,
    int* __restrict__ order, int E)
{
  int e = blockIdx.x * 256 + threadIdx.x;
  if (e >= E) return;
  int pos = atomicAdd(cursor + nbr[2 * e], 1);
  order[pos] = e;
}

// ---------------- canonicalize: wave rank-sort of each atom's segment ----------------
__global__ __launch_bounds__(256) void segsort_kernel(
    int* __restrict__ order, const int* __restrict__ start, int N)
{
  int wi = blockIdx.x * 4 + (threadIdx.x >> 6);
  int lane = threadIdx.x & 63;
  if (wi >= N) return;
  int s0 = start[wi], s1 = start[wi + 1];
  int len = s1 - s0;
  if (len <= 1) return;
  if (len <= 64) {
    int id = (lane < len) ? order[s0 + lane] : 0x7FFFFFFF;
    int rank = 0;
#pragma unroll
    for (int k = 0; k < 64; ++k) {
      int other = __shfl(id, k, 64);
      rank += (other < id) ? 1 : 0;
    }
    if (lane < len) order[s0 + rank] = id;
  } else if (lane == 0) {
    for (int a = s0 + 1; a < s1; ++a) {
      int key = order[a];
      int b = a - 1;
      while (b >= s0 && order[b] > key) { order[b + 1] = order[b]; --b; }
      order[b + 1] = key;
    }
  }
}

// ---------------- geometry gather-fill (deterministic) ----------------
// rbf_h row layout (32 f16): slots 0..19 = sin(k_n d)/d * env   (env pre-folded)
//                            slot  20    = env
//                            slots 21..31 = 0
__global__ __launch_bounds__(256) void geom_fill_kernel(
    const int* __restrict__ order, const int* __restrict__ nbr,
    const float* __restrict__ xyz, int2* __restrict__ ij_s,
    float* __restrict__ unit_s, f16* __restrict__ rbf_h, int E)
{
  int p = blockIdx.x * 256 + threadIdx.x;
  if (p >= E) return;
  int e = order[p];
  int i = nbr[2 * e], j = nbr[2 * e + 1];
  float dx = xyz[3 * j + 0] - xyz[3 * i + 0];
  float dy = xyz[3 * j + 1] - xyz[3 * i + 1];
  float dz = xyz[3 * j + 2] - xyz[3 * i + 2];
  float d2 = dx * dx + dy * dy + dz * dz + 3.0f * EPS_F;  // ref adds EPS per comp
  float d = sqrtf(d2);
  float inv_d = 1.0f / d;
  ij_s[p] = make_int2(i, j);
  unit_s[3 * p + 0] = dx * inv_d;
  unit_s[3 * p + 1] = dy * inv_d;
  unit_s[3 * p + 2] = dz * inv_d;
  float x = d * (PI_F / CUTOFF_F);
  float s1, c1;
  __sincosf(x, &s1, &c1);
  float envv = (d < CUTOFF_F) ? 0.5f * (c1 + 1.0f) : 0.0f;
  f16 tmp[32];
  float two_c = 2.0f * c1;
  float env_inv_d = envv * inv_d;
  float sp = 0.0f, sn = s1;           // Chebyshev recurrence for sin(n*x)
  tmp[0] = (f16)(sn * env_inv_d);
#pragma unroll
  for (int n = 1; n < NRBF; ++n) {
    float nx = two_c * sn - sp;
    sp = sn; sn = nx;
    tmp[n] = (f16)(sn * env_inv_d);
  }
  tmp[NRBF] = (f16)envv;
#pragma unroll
  for (int n = NRBF + 1; n < 32; ++n) tmp[n] = (f16)0.0f;
#pragma unroll
  for (int g = 0; g < 4; ++g)
    *(f16x8*)(rbf_h + (size_t)p * 32 + g * 8) = *(f16x8*)&tmp[g * 8];
}

// ---------------- pre-pack dwx = [dist_w; dist_b; 0] into MFMA B-fragment order ----------------
__global__ __launch_bounds__(256) void dwfrag_kernel(
    const float* __restrict__ dw, const float* __restrict__ db,
    f16* __restrict__ dwf)
{
  int idx = blockIdx.x * 256 + threadIdx.x;
  if (idx >= 3 * 24 * 64 * 8) return;
  int q = idx & 7;
  int lane = (idx >> 3) & 63;
  int ct = (idx >> 9) % 24;
  int l = idx / (24 * 64 * 8);
  int k = (lane >> 4) * 8 + q;
  int col = ct * 16 + (lane & 15);
  float val = 0.f;
  if (k < NRBF) val = dw[(size_t)l * NRBF * 384 + (size_t)k * 384 + col];
  else if (k == NRBF) val = db[(size_t)l * 384 + col];
  dwf[idx] = (f16)val;
}

// ---------------- s = embed[z] (fp32 + f16 mirror) ----------------
__global__ __launch_bounds__(256) void embed_kernel(
    const int* __restrict__ z, const float* __restrict__ embed,
    float* __restrict__ s, f16* __restrict__ s_h, int N)
{
  int idx = blockIdx.x * 256 + threadIdx.x;
  if (idx >= N * 128) return;
  int n = idx >> 7, f = idx & 127;
  float x = embed[z[n] * 128 + f];
  s[idx] = x;
  s_h[idx] = (f16)x;
}

__global__ __launch_bounds__(256) void w1t_kernel(
    const float* __restrict__ w1, f16* __restrict__ w1t)
{
  int idx = blockIdx.x * 256 + threadIdx.x;
  if (idx >= 64 * 128) return;
  int n = idx >> 7, k = idx & 127;
  w1t[idx] = (f16)w1[(size_t)k * 64 + n];
}

// ---------------- f16 MFMA GEMM ----------------
template <bool SILU, int OUT, bool AH>
__global__ __launch_bounds__(256) void gemm_kernel(
    const void* __restrict__ Ap, const float* __restrict__ W,
    const float* __restrict__ bias, const float* __restrict__ rowscale,
    void* __restrict__ Cout, int M, int N, int K)
{
  __shared__ f16 As[64][40];
  __shared__ f16 Bs[64][40];
  int t = threadIdx.x;
  int wave = t >> 6, lane = t & 63;
  int rw = wave & 1, cw = wave >> 1;
  int lr = lane & 15, quad = lane >> 4;
  int row0 = blockIdx.x * 64, col0 = blockIdx.y * 64;
  floatx4 acc[2][2] = {};
  for (int k0 = 0; k0 < K; k0 += 32) {
    if (AH) {
      const f16* A = (const f16*)Ap;
      int sm = t >> 2, sk = (t & 3) * 8;
      f16x8 av;
      if (row0 + sm < M) av = *(const f16x8*)(A + (size_t)(row0 + sm) * K + k0 + sk);
      else { for (int q = 0; q < 8; ++q) av[q] = (f16)0.0f; }
      *(f16x8*)&As[sm][sk] = av;
    } else {
      const float* A = (const float*)Ap;
#pragma unroll
      for (int u0 = 0; u0 < 2; ++u0) {
        int u = t + u0 * 256;
        int m = u >> 3, c4 = (u & 7) * 4;
        float4 av = make_float4(0.f, 0.f, 0.f, 0.f);
        if (row0 + m < M) av = *(const float4*)(A + (size_t)(row0 + m) * K + k0 + c4);
        f16x4 hv;
        hv[0] = (f16)av.x; hv[1] = (f16)av.y; hv[2] = (f16)av.z; hv[3] = (f16)av.w;
        *(f16x4*)&As[m][c4] = hv;
      }
    }
#pragma unroll
    for (int u0 = 0; u0 < 2; ++u0) {
      int u = t + u0 * 256;
      int k = u >> 4, n4 = (u & 15) * 4;
      float4 wv = *(const float4*)(W + (size_t)(k0 + k) * N + col0 + n4);
      Bs[n4 + 0][k] = (f16)wv.x;
      Bs[n4 + 1][k] = (f16)wv.y;
      Bs[n4 + 2][k] = (f16)wv.z;
      Bs[n4 + 3][k] = (f16)wv.w;
    }
    __syncthreads();
    f16x8 af[2], bfr[2];
#pragma unroll
    for (int tr = 0; tr < 2; ++tr)
      af[tr] = *(const f16x8*)&As[rw * 32 + tr * 16 + lr][quad * 8];
#pragma unroll
    for (int tc = 0; tc < 2; ++tc)
      bfr[tc] = *(const f16x8*)&Bs[cw * 32 + tc * 16 + lr][quad * 8];
#pragma unroll
    for (int tr = 0; tr < 2; ++tr)
#pragma unroll
      for (int tc = 0; tc < 2; ++tc)
        acc[tr][tc] = __builtin_amdgcn_mfma_f32_16x16x32_f16(af[tr], bfr[tc], acc[tr][tc], 0, 0, 0);
    __syncthreads();
  }
#pragma unroll
  for (int tc = 0; tc < 2; ++tc) {
    int col = col0 + cw * 32 + tc * 16 + lr;
    float bb = bias ? bias[col] : 0.0f;
#pragma unroll
    for (int tr = 0; tr < 2; ++tr) {
#pragma unroll
      for (int r = 0; r < 4; ++r) {
        int row = row0 + rw * 32 + tr * 16 + quad * 4 + r;
        if (row < M) {
          float x = acc[tr][tc][r] + bb;
          if (rowscale) x *= rowscale[row];
          if (SILU) x = silu_f(x);
          size_t o = (size_t)row * N + col;
          if (OUT == 0) ((float*)Cout)[o] = x;
          else          ((f16*)Cout)[o] = (f16)x;
        }
      }
    }
  }
}

// ---------------- dual-weight f16 MFMA GEMM: C1 = A@W1, C2 = A@W2 (fp32 A/out) ----------------
__global__ __launch_bounds__(256) void gemm_dual_kernel(
    const float* __restrict__ A, const float* __restrict__ W1,
    const float* __restrict__ W2, float* __restrict__ C1, float* __restrict__ C2,
    int M, int N, int K)
{
  __shared__ f16 As[64][40];
  __shared__ f16 Bs1[64][40];
  __shared__ f16 Bs2[64][40];
  int t = threadIdx.x;
  int wave = t >> 6, lane = t & 63;
  int rw = wave & 1, cw = wave >> 1;
  int lr = lane & 15, quad = lane >> 4;
  int row0 = blockIdx.x * 64, col0 = blockIdx.y * 64;
  floatx4 acc1[2][2] = {};
  floatx4 acc2[2][2] = {};
  for (int k0 = 0; k0 < K; k0 += 32) {
#pragma unroll
    for (int u0 = 0; u0 < 2; ++u0) {
      int u = t + u0 * 256;
      int m = u >> 3, c4 = (u & 7) * 4;
      float4 av = make_float4(0.f, 0.f, 0.f, 0.f);
      if (row0 + m < M) av = *(const float4*)(A + (size_t)(row0 + m) * K + k0 + c4);
      f16x4 hv;
      hv[0] = (f16)av.x; hv[1] = (f16)av.y; hv[2] = (f16)av.z; hv[3] = (f16)av.w;
      *(f16x4*)&As[m][c4] = hv;
    }
#pragma unroll
    for (int u0 = 0; u0 < 2; ++u0) {
      int u = t + u0 * 256;
      int k = u >> 4, n4 = (u & 15) * 4;
      float4 wv = *(const float4*)(W1 + (size_t)(k0 + k) * N + col0 + n4);
      Bs1[n4 + 0][k] = (f16)wv.x;
      Bs1[n4 + 1][k] = (f16)wv.y;
      Bs1[n4 + 2][k] = (f16)wv.z;
      Bs1[n4 + 3][k] = (f16)wv.w;
      float4 xv = *(const float4*)(W2 + (size_t)(k0 + k) * N + col0 + n4);
      Bs2[n4 + 0][k] = (f16)xv.x;
      Bs2[n4 + 1][k] = (f16)xv.y;
      Bs2[n4 + 2][k] = (f16)xv.z;
      Bs2[n4 + 3][k] = (f16)xv.w;
    }
    __syncthreads();
    f16x8 af[2], b1[2], b2[2];
#pragma unroll
    for (int tr = 0; tr < 2; ++tr)
      af[tr] = *(const f16x8*)&As[rw * 32 + tr * 16 + lr][quad * 8];
#pragma unroll
    for (int tc = 0; tc < 2; ++tc) {
      b1[tc] = *(const f16x8*)&Bs1[cw * 32 + tc * 16 + lr][quad * 8];
      b2[tc] = *(const f16x8*)&Bs2[cw * 32 + tc * 16 + lr][quad * 8];
    }
#pragma unroll
    for (int tr = 0; tr < 2; ++tr)
#pragma unroll
      for (int tc = 0; tc < 2; ++tc) {
        acc1[tr][tc] = __builtin_amdgcn_mfma_f32_16x16x32_f16(af[tr], b1[tc], acc1[tr][tc], 0, 0, 0);
        acc2[tr][tc] = __builtin_amdgcn_mfma_f32_16x16x32_f16(af[tr], b2[tc], acc2[tr][tc], 0, 0, 0);
      }
    __syncthreads();
  }
#pragma unroll
  for (int tc = 0; tc < 2; ++tc) {
    int col = col0 + cw * 32 + tc * 16 + lr;
#pragma unroll
    for (int tr = 0; tr < 2; ++tr) {
#pragma unroll
      for (int r = 0; r < 4; ++r) {
        int row = row0 + rw * 32 + tr * 16 + quad * 4 + r;
        if (row < M) {
          C1[(size_t)row * N + col] = acc1[tr][tc][r];
          C2[(size_t)row * N + col] = acc2[tr][tc][r];
        }
      }
    }
  }
}

// ---------------- MFMA-ws message kernel (r4 version - best measured: ~87-90us) ----------------
// Phase A: ws_tile[32][384] = rbfA @ dwx via 48 MFMAs.
// Phase B: gather loop with 8-deep register pipeline (named slots).
// r5-r10 restructurings (3-stage pipeline, 12-wave, two-pass LDS, async
// global_load_lds staging) all measured WORSE (112-427us). This is the keeper.
#define MEPB 32
__global__ __launch_bounds__(384, 4) void message_kernel(
    const int2* __restrict__ ij_s, const float* __restrict__ unit_s,
    const f16* __restrict__ rbf_h, const f16* __restrict__ dwf,
    const f16* __restrict__ phi_h, const f16* __restrict__ vh,
    float* __restrict__ s, float* __restrict__ v, int E)
{
  __shared__ f16 rbfA[MEPB][40];
  __shared__ f16 wsT[384][38];
  __shared__ int2 ijL[MEPB];
  __shared__ float unitL[MEPB * 3];
  int t = threadIdx.x;
  int wave = t >> 6, lane = t & 63;
  int e_lo = blockIdx.x * MEPB;
  if (e_lo >= E) return;
  int e_hi = (e_lo + MEPB < E) ? e_lo + MEPB : E;
  int cnt = e_hi - e_lo;

  // ---- B fragments: 4 col-tiles per wave, from frag-ordered dwf ----
  f16x8 bf[4];
#pragma unroll
  for (int i = 0; i < 4; ++i) {
    int ct = wave * 4 + i;
    bf[i] = *(const f16x8*)(dwf + ((size_t)ct * 64 + lane) * 8);
  }
  // ---- stage rbf rows / ij / unit ----
  if (t < MEPB * 4) {
    int r = t >> 2, c8 = (t & 3) * 8;
    f16x8 rv;
    if (e_lo + r < E) rv = *(const f16x8*)(rbf_h + (size_t)(e_lo + r) * 32 + c8);
    else { for (int q = 0; q < 8; ++q) rv[q] = (f16)0.0f; }
    *(f16x8*)&rbfA[r][c8] = rv;
  }
  if (t < cnt) ijL[t] = ij_s[e_lo + t];
  if (t < cnt * 3) unitL[t] = unit_s[(size_t)e_lo * 3 + t];
  __syncthreads();

  // ---- MFMA: 2 row-tiles x 4 col-tiles per wave ----
  int lr = lane & 15, quad = lane >> 4;
  f16x8 af[2];
#pragma unroll
  for (int tr = 0; tr < 2; ++tr)
    af[tr] = *(const f16x8*)&rbfA[tr * 16 + lr][quad * 8];
  floatx4 acc[2][4] = {};
#pragma unroll
  for (int tr = 0; tr < 2; ++tr)
#pragma unroll
    for (int i = 0; i < 4; ++i)
      acc[tr][i] = __builtin_amdgcn_mfma_f32_16x16x32_f16(af[tr], bf[i], acc[tr][i], 0, 0, 0);
  // C/D layout: col = lane&15 (within tile), row = quad*4 + r  -> write transposed
#pragma unroll
  for (int tr = 0; tr < 2; ++tr)
#pragma unroll
    for (int i = 0; i < 4; ++i) {
      int col = (wave * 4 + i) * 16 + lr;
      int er = tr * 16 + quad * 4;
      f16x2 lo2, hi2;
      lo2[0] = (f16)acc[tr][i][0]; lo2[1] = (f16)acc[tr][i][1];
      hi2[0] = (f16)acc[tr][i][2]; hi2[1] = (f16)acc[tr][i][3];
      *(f16x2*)&wsT[col][er]     = lo2;
      *(f16x2*)&wsT[col][er + 2] = hi2;
    }
  __syncthreads();

  // ---- Phase B: gather + segment flush, 8-deep pipeline ----
  int g = t >> 7, f = t & 127;
  float a0 = 0.f, a1 = 0.f, a2 = 0.f;
  int prev_i = -1;
  f16 ph_0 = (f16)0.f, ph_1 = (f16)0.f, ph_2 = (f16)0.f, ph_3 = (f16)0.f;
  f16 ph_4 = (f16)0.f, ph_5 = (f16)0.f, ph_6 = (f16)0.f, ph_7 = (f16)0.f;
  f16 vj0_0 = (f16)0.f, vj1_0 = (f16)0.f, vj2_0 = (f16)0.f;
  f16 vj0_1 = (f16)0.f, vj1_1 = (f16)0.f, vj2_1 = (f16)0.f;
  f16 vj0_2 = (f16)0.f, vj1_2 = (f16)0.f, vj2_2 = (f16)0.f;
  f16 vj0_3 = (f16)0.f, vj1_3 = (f16)0.f, vj2_3 = (f16)0.f;
  f16 vj0_4 = (f16)0.f, vj1_4 = (f16)0.f, vj2_4 = (f16)0.f;
  f16 vj0_5 = (f16)0.f, vj1_5 = (f16)0.f, vj2_5 = (f16)0.f;
  f16 vj0_6 = (f16)0.f, vj1_6 = (f16)0.f, vj2_6 = (f16)0.f;
  f16 vj0_7 = (f16)0.f, vj1_7 = (f16)0.f, vj2_7 = (f16)0.f;

#define MK_LOAD(S, RR) do { int rv_ = (RR); if (rv_ < cnt) {                  \
    int jj_ = ijL[rv_].y;                                                      \
    ph_##S = phi_h[(size_t)jj_ * 384 + t];                                     \
    if (g == 0) { const f16* vp_ = vh + (size_t)jj_ * 384 + f;                 \
      vj0_##S = vp_[0]; vj1_##S = vp_[128]; vj2_##S = vp_[256]; }              \
  } } while (0)

#define MK_PROC(S, RR) do { int rv_ = (RR); if (rv_ < cnt) {                   \
    int ix_ = ijL[rv_].x;                                                      \
    if (ix_ != prev_i) {                                                       \
      if (prev_i >= 0) {                                                       \
        if (g == 1) atomicAdd(s + (size_t)prev_i * 128 + f, a0);               \
        else { float* vb_ = v + (size_t)prev_i * 384 + f;                      \
          atomicAdd(vb_, a0); atomicAdd(vb_ + 128, a1); atomicAdd(vb_ + 256, a2); } \
        a0 = a1 = a2 = 0.f; }                                                  \
      prev_i = ix_; }                                                          \
    float ws_ = (float)wsT[t][rv_];                                            \
    float inv_ = (float)ph_##S * ws_;                                          \
    if (g == 0) { a0 = fmaf(inv_, (float)vj0_##S, a0);                         \
                  a1 = fmaf(inv_, (float)vj1_##S, a1);                         \
                  a2 = fmaf(inv_, (float)vj2_##S, a2); }                       \
    else if (g == 1) { a0 += inv_; }                                           \
    else { a0 = fmaf(inv_, unitL[3 * rv_ + 0], a0);                            \
           a1 = fmaf(inv_, unitL[3 * rv_ + 1], a1);                            \
           a2 = fmaf(inv_, unitL[3 * rv_ + 2], a2); }                          \
  } } while (0)

  MK_LOAD(0, 0); MK_LOAD(1, 1); MK_LOAD(2, 2); MK_LOAD(3, 3);
  MK_LOAD(4, 4); MK_LOAD(5, 5); MK_LOAD(6, 6); MK_LOAD(7, 7);
  for (int r = 0; r < cnt; r += 8) {
    MK_PROC(0, r);     MK_LOAD(0, r + 8);
    MK_PROC(1, r + 1); MK_LOAD(1, r + 9);
    MK_PROC(2, r + 2); MK_LOAD(2, r + 10);
    MK_PROC(3, r + 3); MK_LOAD(3, r + 11);
    MK_PROC(4, r + 4); MK_LOAD(4, r + 12);
    MK_PROC(5, r + 5); MK_LOAD(5, r + 13);
    MK_PROC(6, r + 6); MK_LOAD(6, r + 14);
    MK_PROC(7, r + 7); MK_LOAD(7, r + 15);
  }
#undef MK_LOAD
#undef MK_PROC
  // ---- final flush ----
  if (prev_i >= 0) {
    if (g == 1) {
      atomicAdd(s + (size_t)prev_i * 128 + f, a0);
    } else {
      float* vb = v + (size_t)prev_i * 384 + f;
      atomicAdd(vb, a0);
      atomicAdd(vb + 128, a1);
      atomicAdd(vb + 256, a2);
    }
  }
}

// ---------------- s_stack = [s, ||v_v||] (f16 out) ----------------
__global__ __launch_bounds__(256) void stack_kernel(
    const float* __restrict__ s, const float* __restrict__ v_v,
    f16* __restrict__ s_stack, int N)
{
  int idx = blockIdx.x * 256 + threadIdx.x;
  if (idx >= N * 128) return;
  int n = idx >> 7, g = idx & 127;
  float a = v_v[(size_t)n * 384 + g];
  float b = v_v[(size_t)n * 384 + 128 + g];
  float c = v_v[(size_t)n * 384 + 256 + g];
  s_stack[(size_t)n * 256 + g] = (f16)s[idx];
  s_stack[(size_t)n * 256 + 128 + g] = (f16)sqrtf(a * a + b * b + c * c + EPS_F);
}

// ---------------- gated update of s, v (+ f16 mirrors for next-layer reads) ----------------
__global__ __launch_bounds__(256) void apply_kernel(
    float* __restrict__ s, f16* __restrict__ s_h,
    float* __restrict__ v, f16* __restrict__ v_h,
    const float* __restrict__ u_v, const float* __restrict__ v_v,
    const float* __restrict__ sp, int N)
{
  int idx = blockIdx.x * 256 + threadIdx.x;
  if (idx >= N * 128) return;
  int n = idx >> 7, g = idx & 127;
  float sp0 = sp[(size_t)n * 384 + g];
  float sp1 = sp[(size_t)n * 384 + 128 + g];
  float sp2 = sp[(size_t)n * 384 + 256 + g];
  float dot = 0.f;
#pragma unroll
  for (int c = 0; c < 3; ++c) {
    size_t o = (size_t)n * 384 + c * 128 + g;
    float uv = u_v[o];
    float vn = fmaf(uv, sp0, v[o]);
    v[o] = vn;
    v_h[o] = (f16)vn;
    dot = fmaf(uv, v_v[o], dot);
  }
  float sn = s[idx] + dot * sp1 + sp2;
  s[idx] = sn;
  s_h[idx] = (f16)sn;
}

// ---------------- fused f16 MFMA readout (unsorted edges; register-prefetched gathers) ----------------
__global__ __launch_bounds__(256) void readout_gemm_kernel(
    const int* __restrict__ nbr, const float* __restrict__ xyz,
    const f16* __restrict__ s_h, const f16* __restrict__ w1t,
    const float* __restrict__ b1, const float* __restrict__ w2,
    const float* __restrict__ b2, float* __restrict__ out, int E)
{
  __shared__ f16 As[64][40];
  __shared__ f16 Bs[64][40];
  __shared__ float red[2][64];
  __shared__ int ijc[64][2];
  int t = threadIdx.x;
  int wave = t >> 6, lane = t & 63;
  int rw = wave & 1, cw = wave >> 1;
  int lr = lane & 15, quad = lane >> 4;
  int e0b = blockIdx.x * 64;
  if (t < 64) {
    int e = e0b + t;
    if (e < E) { ijc[t][0] = nbr[2 * e]; ijc[t][1] = nbr[2 * e + 1]; }
    else { ijc[t][0] = 0; ijc[t][1] = 0; }
  }
  __syncthreads();
  int m = t >> 2;             // one row (edge) per thread
  int c8 = (t & 3) * 8;       // 8 features within 32-k window
  int im = ijc[m][0], jm = ijc[m][1];
  bool okm = (e0b + m) < E;
  // prefetch all 8 row-segments (4 windows x i/j) - independent loads in flight
  f16x8 xa[4], ya[4];
  if (okm) {
#pragma unroll
    for (int w = 0; w < 4; ++w) {
      xa[w] = *(const f16x8*)(s_h + (size_t)im * 128 + w * 32 + c8);
      ya[w] = *(const f16x8*)(s_h + (size_t)jm * 128 + w * 32 + c8);
    }
  } else {
#pragma unroll
    for (int w = 0; w < 4; ++w)
      for (int q = 0; q < 8; ++q) { xa[w][q] = (f16)0.0f; ya[w][q] = (f16)0.0f; }
  }
  floatx4 acc[2][2] = {};
#pragma unroll
  for (int w = 0; w < 4; ++w) {
    *(f16x8*)&As[m][c8] = xa[w] + ya[w];
    {
      int sm = t >> 2, sk = (t & 3) * 8;
      *(f16x8*)&Bs[sm][sk] = *(const f16x8*)(w1t + (size_t)sm * 128 + w * 32 + sk);
    }
    __syncthreads();
    f16x8 af[2], bfr[2];
#pragma unroll
    for (int tr = 0; tr < 2; ++tr)
      af[tr] = *(const f16x8*)&As[rw * 32 + tr * 16 + lr][quad * 8];
#pragma unroll
    for (int tc = 0; tc < 2; ++tc)
      bfr[tc] = *(const f16x8*)&Bs[cw * 32 + tc * 16 + lr][quad * 8];
#pragma unroll
    for (int tr = 0; tr < 2; ++tr)
#pragma unroll
      for (int tc = 0; tc < 2; ++tc)
        acc[tr][tc] = __builtin_amdgcn_mfma_f32_16x16x32_f16(af[tr], bfr[tc], acc[tr][tc], 0, 0, 0);
    __syncthreads();
  }
  float b1v[2], w2v[2];
#pragma unroll
  for (int tc = 0; tc < 2; ++tc) {
    int col = cw * 32 + tc * 16 + lr;
    b1v[tc] = b1[col];
    w2v[tc] = w2[col];
  }
#pragma unroll
  for (int tr = 0; tr < 2; ++tr) {
#pragma unroll
    for (int r = 0; r < 4; ++r) {
      float p = 0.f;
#pragma unroll
      for (int tc = 0; tc < 2; ++tc)
        p += silu_f(acc[tr][tc][r] + b1v[tc]) * w2v[tc];
#pragma unroll
      for (int ofs = 1; ofs < 16; ofs <<= 1) p += __shfl_xor(p, ofs, 64);
      if (lr == 0) red[cw][rw * 32 + tr * 16 + quad * 4 + r] = p;
    }
  }
  __syncthreads();
  if (t < 64) {
    int e = e0b + t;
    if (e < E) {
      float fs = red[0][t] + red[1][t] + b2[0];
      int i = ijc[t][0], j = ijc[t][1];
      float dx = xyz[3 * i + 0] - xyz[3 * j + 0];
      float dy = xyz[3 * i + 1] - xyz[3 * j + 1];
      float dz = xyz[3 * i + 2] - xyz[3 * j + 2];
      float dis = sqrtf(dx * dx + dy * dy + dz * dz);  // no EPS here (matches ref)
      float sc = fs / dis;
      float fx = sc * dx, fy = sc * dy, fz = sc * dz;
      atomicAdd(out + (size_t)i * 3 + 0, fx);
      atomicAdd(out + (size_t)i * 3 + 1, fy);
      atomicAdd(out + (size_t)i * 3 + 2, fz);
      atomicAdd(out + (size_t)j * 3 + 0, -fx);
      atomicAdd(out + (size_t)j * 3 + 1, -fy);
      atomicAdd(out + (size_t)j * 3 + 2, -fz);
    }
  }
}

extern "C" void kernel_launch(void* const* d_in, const int* in_sizes, int n_in,
                              void* d_out, int out_size, void* d_ws, size_t ws_size,
                              hipStream_t stream) {
  const float* xyz    = (const float*)d_in[0];
  const int*   z      = (const int*)d_in[1];
  const int*   nbr    = (const int*)d_in[2];
  const float* embed  = (const float*)d_in[3];
  const float* msg_w1 = (const float*)d_in[4];
  const float* msg_b1 = (const float*)d_in[5];
  const float* msg_w2 = (const float*)d_in[6];
  const float* msg_b2 = (const float*)d_in[7];
  const float* dist_w = (const float*)d_in[8];
  const float* dist_b = (const float*)d_in[9];
  const float* upd_u  = (const float*)d_in[10];
  const float* upd_v  = (const float*)d_in[11];
  const float* upd_w1 = (const float*)d_in[12];
  const float* upd_b1 = (const float*)d_in[13];
  const float* upd_w2 = (const float*)d_in[14];
  const float* upd_b2 = (const float*)d_in[15];
  const float* ero_w1 = (const float*)d_in[16];
  const float* ero_b1 = (const float*)d_in[17];
  const float* ero_w2 = (const float*)d_in[18];
  const float* ero_b2 = (const float*)d_in[19];

  const int N = in_sizes[1];      // 10000
  const int E = in_sizes[2] / 2;  // 160000
  const int L = 3;

  char* ws = (char*)d_ws;
  size_t off = 0;
  auto alloc = [&](size_t bytes) -> void* {
    void* p = ws + off;
    off += (bytes + 255) & ~(size_t)255;
    return p;
  };
  float* unit_s = (float*)alloc((size_t)E * 3 * 4);
  f16*   rbf_h  = (f16*)alloc((size_t)E * 32 * 2);
  int2*  ij_s   = (int2*)alloc((size_t)E * 8);
  int*   order  = (int*)alloc((size_t)E * 4);
  float* s      = (float*)alloc((size_t)N * 128 * 4);
  f16*   s_h    = (f16*)alloc((size_t)N * 128 * 2);
  float* vA     = (float*)alloc((size_t)N * 384 * 4);
  f16*   vhA    = (f16*)alloc((size_t)N * 384 * 2);
  f16*   phi_h  = (f16*)alloc((size_t)N * 384 * 2);
  f16*   w1t    = (f16*)alloc((size_t)64 * 128 * 2);
  f16*   dwf    = (f16*)alloc((size_t)3 * 24 * 64 * 8 * 2);
  int*   histx  = (int*)alloc((size_t)(N + 1) * 4);
  int*   startp = (int*)alloc((size_t)(N + 1) * 4);
  int*   cursor = (int*)alloc((size_t)N * 4);
  float* u_v    = (float*)alloc((size_t)N * 384 * 4);
  float* v_v    = (float*)alloc((size_t)N * 384 * 4);
  float* sp     = (float*)alloc((size_t)N * 384 * 4);
  f16*   sstk_h = (f16*)alloc((size_t)N * 256 * 2);
  f16*   h_h    = (f16*)alloc((size_t)N * 128 * 2);

  auto cdiv = [](int a, int b) { return (a + b - 1) / b; };

  // ---- setup: deterministic CSR + weight pre-pack ----
  hipMemsetAsync(vA, 0, (size_t)N * 384 * 4, stream);
  hipMemsetAsync(vhA, 0, (size_t)N * 384 * 2, stream);
  hipMemsetAsync(histx, 0, (size_t)(N + 1) * 4, stream);
  hist_kernel<<<cdiv(E, 256), 256, 0, stream>>>(nbr, histx, E);
  scan_kernel<<<1, 1024, 0, stream>>>(histx, startp, cursor, N);
  scatter_id_kernel<<<cdiv(E, 256), 256, 0, stream>>>(nbr, cursor, order, E);
  segsort_kernel<<<cdiv(N, 4), 256, 0, stream>>>(order, startp, N);
  geom_fill_kernel<<<cdiv(E, 256), 256, 0, stream>>>(
      order, nbr, xyz, ij_s, unit_s, rbf_h, E);
  embed_kernel<<<cdiv(N * 128, 256), 256, 0, stream>>>(z, embed, s, s_h, N);
  w1t_kernel<<<cdiv(64 * 128, 256), 256, 0, stream>>>(ero_w1, w1t);
  dwfrag_kernel<<<cdiv(3 * 24 * 64 * 8, 256), 256, 0, stream>>>(dist_w, dist_b, dwf);

  for (int l = 0; l < L; ++l) {
    // phi = silu(s @ msg_w1 + b1) @ msg_w2 + b2  -> f16 (A read from f16 mirror)
    gemm_kernel<true, 1, true><<<dim3(cdiv(N, 64), 2), 256, 0, stream>>>(
        s_h, msg_w1 + (size_t)l * 128 * 128, msg_b1 + (size_t)l * 128, nullptr, h_h, N, 128, 128);
    gemm_kernel<false, 1, true><<<dim3(cdiv(N, 64), 6), 256, 0, stream>>>(
        h_h, msg_w2 + (size_t)l * 128 * 384, msg_b2 + (size_t)l * 384, nullptr, phi_h, N, 384, 128);
    // MFMA-ws message; atomic flush into s / v (in place)
    message_kernel<<<cdiv(E, MEPB), 384, 0, stream>>>(
        ij_s, unit_s, rbf_h, dwf + (size_t)l * 24 * 64 * 8,
        phi_h, vhA, s, vA, E);
    // update block
    gemm_dual_kernel<<<dim3(cdiv(N * 3, 64), 2), 256, 0, stream>>>(
        vA, upd_u + (size_t)l * 128 * 128, upd_v + (size_t)l * 128 * 128,
        u_v, v_v, N * 3, 128, 128);
    stack_kernel<<<cdiv(N * 128, 256), 256, 0, stream>>>(s, v_v, sstk_h, N);
    gemm_kernel<true, 1, true><<<dim3(cdiv(N, 64), 2), 256, 0, stream>>>(
        sstk_h, upd_w1 + (size_t)l * 256 * 128, upd_b1 + (size_t)l * 128, nullptr, h_h, N, 128, 256);
    gemm_kernel<false, 0, true><<<dim3(cdiv(N, 64), 6), 256, 0, stream>>>(
        h_h, upd_w2 + (size_t)l * 128 * 384, upd_b2 + (size_t)l * 384, nullptr, sp, N, 384, 128);
    apply_kernel<<<cdiv(N * 128, 256), 256, 0, stream>>>(
        s, s_h, vA, vhA, u_v, v_v, sp, N);
  }

  // fused f16 MFMA readout (unsorted edges, register-prefetched gathers)
  hipMemsetAsync(d_out, 0, (size_t)out_size * 4, stream);
  readout_gemm_kernel<<<cdiv(E, 64), 256, 0, stream>>>(
      nbr, xyz, s_h, w1t, ero_b1, ero_w2, ero_b2, (float*)d_out, E);
}

// Round 12
// 658.320 us; speedup vs baseline: 2.6311x; 1.0884x over previous
//
#include <hip/hip_runtime.h>
#include <math.h>

#define EPS_F 1e-15f
#define NRBF 20
#define CUTOFF_F 5.0f
#define PI_F 3.14159265358979323846f

typedef unsigned short u16;
typedef _Float16 f16;
typedef f16 f16x8 __attribute__((ext_vector_type(8)));
typedef f16 f16x4 __attribute__((ext_vector_type(4)));
typedef f16 f16x2 __attribute__((ext_vector_type(2)));
typedef float floatx4 __attribute__((ext_vector_type(4)));

__device__ __forceinline__ float silu_f(float x) { return x / (1.0f + expf(-x)); }

// ---------------- counting sort: histogram + scan ----------------
__global__ __launch_bounds__(256) void hist_kernel(
    const int* __restrict__ nbr, int* __restrict__ hist, int E)
{
  int e = blockIdx.x * 256 + threadIdx.x;
  if (e >= E) return;
  atomicAdd(hist + nbr[2 * e], 1);
}

// single-block exclusive scan, wave-shfl based (few barriers)
__global__ __launch_bounds__(1024) void scan_kernel(
    const int* __restrict__ hist, int* __restrict__ start,
    int* __restrict__ cursor, int N)
{
  __shared__ int wsum[16];
  __shared__ int carry_s;
  int tid = threadIdx.x;
  int lane = tid & 63, wid = tid >> 6;
  if (tid == 0) carry_s = 0;
  __syncthreads();
  for (int base = 0; base < N; base += 1024) {
    int x = (base + tid < N) ? hist[base + tid] : 0;
    int v = x;
#pragma unroll
    for (int o = 1; o < 64; o <<= 1) {
      int t2 = __shfl_up(v, o, 64);
      if (lane >= o) v += t2;
    }
    if (lane == 63) wsum[wid] = v;
    __syncthreads();
    if (tid < 16) {
      int w = wsum[tid];
#pragma unroll
      for (int o = 1; o < 16; o <<= 1) {
        int t2 = __shfl_up(w, o, 64);
        if (tid >= o) w += t2;
      }
      wsum[tid] = w;
    }
    __syncthreads();
    int wbase = (wid == 0) ? 0 : wsum[wid - 1];
    int incl = v + wbase;
    int carry = carry_s;
    if (base + tid < N) {
      int ex = carry + incl - x;
      start[base + tid] = ex;
      cursor[base + tid] = ex;
    }
    __syncthreads();
    if (tid == 1023) carry_s = carry + incl;
    __syncthreads();
  }
  if (tid == 0) start[N] = carry_s;
}

// ---------------- scatter edge IDs ----------------
__global__ __launch_bounds__(256) void scatter_id_kernel(
    const int* __restrict__ nbr, int* __restrict__ cursor,
    int* __restrict__ order, int E)
{
  int e = blockIdx.x * 256 + threadIdx.x;
  if (e >= E) return;
  int pos = atomicAdd(cursor + nbr[2 * e], 1);
  order[pos] = e;
}

// ---------------- canonicalize: wave rank-sort of each atom's segment ----------------
__global__ __launch_bounds__(256) void segsort_kernel(
    int* __restrict__ order, const int* __restrict__ start, int N)
{
  int wi = blockIdx.x * 4 + (threadIdx.x >> 6);
  int lane = threadIdx.x & 63;
  if (wi >= N) return;
  int s0 = start[wi], s1 = start[wi + 1];
  int len = s1 - s0;
  if (len <= 1) return;
  if (len <= 64) {
    int id = (lane < len) ? order[s0 + lane] : 0x7FFFFFFF;
    int rank = 0;
#pragma unroll
    for (int k = 0; k < 64; ++k) {
      int other = __shfl(id, k, 64);
      rank += (other < id) ? 1 : 0;
    }
    if (lane < len) order[s0 + rank] = id;
  } else if (lane == 0) {
    for (int a = s0 + 1; a < s1; ++a) {
      int key = order[a];
      int b = a - 1;
      while (b >= s0 && order[b] > key) { order[b + 1] = order[b]; --b; }
      order[b + 1] = key;
    }
  }
}

// ---------------- geometry gather-fill (deterministic) ----------------
// rbf_h row layout (32 f16): slots 0..19 = sin(k_n d)/d * env   (env pre-folded)
//                            slot  20    = env
//                            slots 21..31 = 0
__global__ __launch_bounds__(256) void geom_fill_kernel(
    const int* __restrict__ order, const int* __restrict__ nbr,
    const float* __restrict__ xyz, int2* __restrict__ ij_s,
    float* __restrict__ unit_s, f16* __restrict__ rbf_h, int E)
{
  int p = blockIdx.x * 256 + threadIdx.x;
  if (p >= E) return;
  int e = order[p];
  int i = nbr[2 * e], j = nbr[2 * e + 1];
  float dx = xyz[3 * j + 0] - xyz[3 * i + 0];
  float dy = xyz[3 * j + 1] - xyz[3 * i + 1];
  float dz = xyz[3 * j + 2] - xyz[3 * i + 2];
  float d2 = dx * dx + dy * dy + dz * dz + 3.0f * EPS_F;  // ref adds EPS per comp
  float d = sqrtf(d2);
  float inv_d = 1.0f / d;
  ij_s[p] = make_int2(i, j);
  unit_s[3 * p + 0] = dx * inv_d;
  unit_s[3 * p + 1] = dy * inv_d;
  unit_s[3 * p + 2] = dz * inv_d;
  float x = d * (PI_F / CUTOFF_F);
  float s1, c1;
  __sincosf(x, &s1, &c1);
  float envv = (d < CUTOFF_F) ? 0.5f * (c1 + 1.0f) : 0.0f;
  f16 tmp[32];
  float two_c = 2.0f * c1;
  float env_inv_d = envv * inv_d;
  float sp = 0.0f, sn = s1;           // Chebyshev recurrence for sin(n*x)
  tmp[0] = (f16)(sn * env_inv_d);
#pragma unroll
  for (int n = 1; n < NRBF; ++n) {
    float nx = two_c * sn - sp;
    sp = sn; sn = nx;
    tmp[n] = (f16)(sn * env_inv_d);
  }
  tmp[NRBF] = (f16)envv;
#pragma unroll
  for (int n = NRBF + 1; n < 32; ++n) tmp[n] = (f16)0.0f;
#pragma unroll
  for (int g = 0; g < 4; ++g)
    *(f16x8*)(rbf_h + (size_t)p * 32 + g * 8) = *(f16x8*)&tmp[g * 8];
}

// ---------------- pre-pack dwx = [dist_w; dist_b; 0] into MFMA B-fragment order ----------------
__global__ __launch_bounds__(256) void dwfrag_kernel(
    const float* __restrict__ dw, const float* __restrict__ db,
    f16* __restrict__ dwf)
{
  int idx = blockIdx.x * 256 + threadIdx.x;
  if (idx >= 3 * 24 * 64 * 8) return;
  int q = idx & 7;
  int lane = (idx >> 3) & 63;
  int ct = (idx >> 9) % 24;
  int l = idx / (24 * 64 * 8);
  int k = (lane >> 4) * 8 + q;
  int col = ct * 16 + (lane & 15);
  float val = 0.f;
  if (k < NRBF) val = dw[(size_t)l * NRBF * 384 + (size_t)k * 384 + col];
  else if (k == NRBF) val = db[(size_t)l * 384 + col];
  dwf[idx] = (f16)val;
}

// ---------------- s = embed[z] (fp32 + f16 mirror) ----------------
__global__ __launch_bounds__(256) void embed_kernel(
    const int* __restrict__ z, const float* __restrict__ embed,
    float* __restrict__ s, f16* __restrict__ s_h, int N)
{
  int idx = blockIdx.x * 256 + threadIdx.x;
  if (idx >= N * 128) return;
  int n = idx >> 7, f = idx & 127;
  float x = embed[z[n] * 128 + f];
  s[idx] = x;
  s_h[idx] = (f16)x;
}

__global__ __launch_bounds__(256) void w1t_kernel(
    const float* __restrict__ w1, f16* __restrict__ w1t)
{
  int idx = blockIdx.x * 256 + threadIdx.x;
  if (idx >= 64 * 128) return;
  int n = idx >> 7, k = idx & 127;
  w1t[idx] = (f16)w1[(size_t)k * 64 + n];
}

// ---------------- f16 MFMA GEMM ----------------
template <bool SILU, int OUT, bool AH>
__global__ __launch_bounds__(256) void gemm_kernel(
    const void* __restrict__ Ap, const float* __restrict__ W,
    const float* __restrict__ bias, const float* __restrict__ rowscale,
    void* __restrict__ Cout, int M, int N, int K)
{
  __shared__ f16 As[64][40];
  __shared__ f16 Bs[64][40];
  int t = threadIdx.x;
  int wave = t >> 6, lane = t & 63;
  int rw = wave & 1, cw = wave >> 1;
  int lr = lane & 15, quad = lane >> 4;
  int row0 = blockIdx.x * 64, col0 = blockIdx.y * 64;
  floatx4 acc[2][2] = {};
  for (int k0 = 0; k0 < K; k0 += 32) {
    if (AH) {
      const f16* A = (const f16*)Ap;
      int sm = t >> 2, sk = (t & 3) * 8;
      f16x8 av;
      if (row0 + sm < M) av = *(const f16x8*)(A + (size_t)(row0 + sm) * K + k0 + sk);
      else { for (int q = 0; q < 8; ++q) av[q] = (f16)0.0f; }
      *(f16x8*)&As[sm][sk] = av;
    } else {
      const float* A = (const float*)Ap;
#pragma unroll
      for (int u0 = 0; u0 < 2; ++u0) {
        int u = t + u0 * 256;
        int m = u >> 3, c4 = (u & 7) * 4;
        float4 av = make_float4(0.f, 0.f, 0.f, 0.f);
        if (row0 + m < M) av = *(const float4*)(A + (size_t)(row0 + m) * K + k0 + c4);
        f16x4 hv;
        hv[0] = (f16)av.x; hv[1] = (f16)av.y; hv[2] = (f16)av.z; hv[3] = (f16)av.w;
        *(f16x4*)&As[m][c4] = hv;
      }
    }
#pragma unroll
    for (int u0 = 0; u0 < 2; ++u0) {
      int u = t + u0 * 256;
      int k = u >> 4, n4 = (u & 15) * 4;
      float4 wv = *(const float4*)(W + (size_t)(k0 + k) * N + col0 + n4);
      Bs[n4 + 0][k] = (f16)wv.x;
      Bs[n4 + 1][k] = (f16)wv.y;
      Bs[n4 + 2][k] = (f16)wv.z;
      Bs[n4 + 3][k] = (f16)wv.w;
    }
    __syncthreads();
    f16x8 af[2], bfr[2];
#pragma unroll
    for (int tr = 0; tr < 2; ++tr)
      af[tr] = *(const f16x8*)&As[rw * 32 + tr * 16 + lr][quad * 8];
#pragma unroll
    for (int tc = 0; tc < 2; ++tc)
      bfr[tc] = *(const f16x8*)&Bs[cw * 32 + tc * 16 + lr][quad * 8];
#pragma unroll
    for (int tr = 0; tr < 2; ++tr)
#pragma unroll
      for (int tc = 0; tc < 2; ++tc)
        acc[tr][tc] = __builtin_amdgcn_mfma_f32_16x16x32_f16(af[tr], bfr[tc], acc[tr][tc], 0, 0, 0);
    __syncthreads();
  }
#pragma unroll
  for (int tc = 0; tc < 2; ++tc) {
    int col = col0 + cw * 32 + tc * 16 + lr;
    float bb = bias ? bias[col] : 0.0f;
#pragma unroll
    for (int tr = 0; tr < 2; ++tr) {
#pragma unroll
      for (int r = 0; r < 4; ++r) {
        int row = row0 + rw * 32 + tr * 16 + quad * 4 + r;
        if (row < M) {
          float x = acc[tr][tc][r] + bb;
          if (rowscale) x *= rowscale[row];
          if (SILU) x = silu_f(x);
          size_t o = (size_t)row * N + col;
          if (OUT == 0) ((float*)Cout)[o] = x;
          else          ((f16*)Cout)[o] = (f16)x;
        }
      }
    }
  }
}

// ---------------- dual-weight f16 MFMA GEMM: C1 = A@W1, C2 = A@W2 (fp32 A/out) ----------------
__global__ __launch_bounds__(256) void gemm_dual_kernel(
    const float* __restrict__ A, const float* __restrict__ W1,
    const float* __restrict__ W2, float* __restrict__ C1, float* __restrict__ C2,
    int M, int N, int K)
{
  __shared__ f16 As[64][40];
  __shared__ f16 Bs1[64][40];
  __shared__ f16 Bs2[64][40];
  int t = threadIdx.x;
  int wave = t >> 6, lane = t & 63;
  int rw = wave & 1, cw = wave >> 1;
  int lr = lane & 15, quad = lane >> 4;
  int row0 = blockIdx.x * 64, col0 = blockIdx.y * 64;
  floatx4 acc1[2][2] = {};
  floatx4 acc2[2][2] = {};
  for (int k0 = 0; k0 < K; k0 += 32) {
#pragma unroll
    for (int u0 = 0; u0 < 2; ++u0) {
      int u = t + u0 * 256;
      int m = u >> 3, c4 = (u & 7) * 4;
      float4 av = make_float4(0.f, 0.f, 0.f, 0.f);
      if (row0 + m < M) av = *(const float4*)(A + (size_t)(row0 + m) * K + k0 + c4);
      f16x4 hv;
      hv[0] = (f16)av.x; hv[1] = (f16)av.y; hv[2] = (f16)av.z; hv[3] = (f16)av.w;
      *(f16x4*)&As[m][c4] = hv;
    }
#pragma unroll
    for (int u0 = 0; u0 < 2; ++u0) {
      int u = t + u0 * 256;
      int k = u >> 4, n4 = (u & 15) * 4;
      float4 wv = *(const float4*)(W1 + (size_t)(k0 + k) * N + col0 + n4);
      Bs1[n4 + 0][k] = (f16)wv.x;
      Bs1[n4 + 1][k] = (f16)wv.y;
      Bs1[n4 + 2][k] = (f16)wv.z;
      Bs1[n4 + 3][k] = (f16)wv.w;
      float4 xv = *(const float4*)(W2 + (size_t)(k0 + k) * N + col0 + n4);
      Bs2[n4 + 0][k] = (f16)xv.x;
      Bs2[n4 + 1][k] = (f16)xv.y;
      Bs2[n4 + 2][k] = (f16)xv.z;
      Bs2[n4 + 3][k] = (f16)xv.w;
    }
    __syncthreads();
    f16x8 af[2], b1[2], b2[2];
#pragma unroll
    for (int tr = 0; tr < 2; ++tr)
      af[tr] = *(const f16x8*)&As[rw * 32 + tr * 16 + lr][quad * 8];
#pragma unroll
    for (int tc = 0; tc < 2; ++tc) {
      b1[tc] = *(const f16x8*)&Bs1[cw * 32 + tc * 16 + lr][quad * 8];
      b2[tc] = *(const f16x8*)&Bs2[cw * 32 + tc * 16 + lr][quad * 8];
    }
#pragma unroll
    for (int tr = 0; tr < 2; ++tr)
#pragma unroll
      for (int tc = 0; tc < 2; ++tc) {
        acc1[tr][tc] = __builtin_amdgcn_mfma_f32_16x16x32_f16(af[tr], b1[tc], acc1[tr][tc], 0, 0, 0);
        acc2[tr][tc] = __builtin_amdgcn_mfma_f32_16x16x32_f16(af[tr], b2[tc], acc2[tr][tc], 0, 0, 0);
      }
    __syncthreads();
  }
#pragma unroll
  for (int tc = 0; tc < 2; ++tc) {
    int col = col0 + cw * 32 + tc * 16 + lr;
#pragma unroll
    for (int tr = 0; tr < 2; ++tr) {
#pragma unroll
      for (int r = 0; r < 4; ++r) {
        int row = row0 + rw * 32 + tr * 16 + quad * 4 + r;
        if (row < M) {
          C1[(size_t)row * N + col] = acc1[tr][tc][r];
          C2[(size_t)row * N + col] = acc2[tr][tc][r];
        }
      }
    }
  }
}

// ---------------- MFMA-ws message kernel (r4 structure; FULL-tile specialization) ----------------
// r4 = best measured (~90us). ONE change this round: E%MEPB==0 here, so cnt
// is always 32 -> template<FULL> makes cnt compile-time. All `rv_<cnt` guards
// constant-fold: PROC guards vanish, out-of-range prefetch LOADs are DCE'd.
// Removes the block-uniform scalar branches AROUND every pipelined load,
// which force conservative vmcnt placement. Structure/LDS/occupancy identical.
// Tail (E%MEPB!=0) handled by a FULL=false launch with e_base offset.
#define MEPB 32
template <bool FULL>
__global__ __launch_bounds__(384, 4) void message_kernel(
    const int2* __restrict__ ij_s, const float* __restrict__ unit_s,
    const f16* __restrict__ rbf_h, const f16* __restrict__ dwf,
    const f16* __restrict__ phi_h, const f16* __restrict__ vh,
    float* __restrict__ s, float* __restrict__ v, int E, int e_base)
{
  __shared__ f16 rbfA[MEPB][40];
  __shared__ f16 wsT[384][38];
  __shared__ int2 ijL[MEPB];
  __shared__ float unitL[MEPB * 3];
  int t = threadIdx.x;
  int wave = t >> 6, lane = t & 63;
  int e_lo = e_base + blockIdx.x * MEPB;
  if (e_lo >= E) return;
  int cnt;
  if (FULL) cnt = MEPB;                       // compile-time constant
  else      cnt = (e_lo + MEPB < E) ? MEPB : E - e_lo;

  // ---- B fragments: 4 col-tiles per wave, from frag-ordered dwf ----
  f16x8 bf[4];
#pragma unroll
  for (int i = 0; i < 4; ++i) {
    int ct = wave * 4 + i;
    bf[i] = *(const f16x8*)(dwf + ((size_t)ct * 64 + lane) * 8);
  }
  // ---- stage rbf rows / ij / unit ----
  if (t < MEPB * 4) {
    int r = t >> 2, c8 = (t & 3) * 8;
    f16x8 rv;
    if (FULL || e_lo + r < E) rv = *(const f16x8*)(rbf_h + (size_t)(e_lo + r) * 32 + c8);
    else { for (int q = 0; q < 8; ++q) rv[q] = (f16)0.0f; }
    *(f16x8*)&rbfA[r][c8] = rv;
  }
  if (t < cnt) ijL[t] = ij_s[e_lo + t];
  if (t < cnt * 3) unitL[t] = unit_s[(size_t)e_lo * 3 + t];
  __syncthreads();

  // ---- MFMA: 2 row-tiles x 4 col-tiles per wave ----
  int lr = lane & 15, quad = lane >> 4;
  f16x8 af[2];
#pragma unroll
  for (int tr = 0; tr < 2; ++tr)
    af[tr] = *(const f16x8*)&rbfA[tr * 16 + lr][quad * 8];
  floatx4 acc[2][4] = {};
#pragma unroll
  for (int tr = 0; tr < 2; ++tr)
#pragma unroll
    for (int i = 0; i < 4; ++i)
      acc[tr][i] = __builtin_amdgcn_mfma_f32_16x16x32_f16(af[tr], bf[i], acc[tr][i], 0, 0, 0);
  // C/D layout: col = lane&15 (within tile), row = quad*4 + r  -> write transposed
#pragma unroll
  for (int tr = 0; tr < 2; ++tr)
#pragma unroll
    for (int i = 0; i < 4; ++i) {
      int col = (wave * 4 + i) * 16 + lr;
      int er = tr * 16 + quad * 4;
      f16x2 lo2, hi2;
      lo2[0] = (f16)acc[tr][i][0]; lo2[1] = (f16)acc[tr][i][1];
      hi2[0] = (f16)acc[tr][i][2]; hi2[1] = (f16)acc[tr][i][3];
      *(f16x2*)&wsT[col][er]     = lo2;
      *(f16x2*)&wsT[col][er + 2] = hi2;
    }
  __syncthreads();

  // ---- Phase B: gather + segment flush, 8-deep pipeline ----
  int g = t >> 7, f = t & 127;
  float a0 = 0.f, a1 = 0.f, a2 = 0.f;
  int prev_i = -1;
  f16 ph_0 = (f16)0.f, ph_1 = (f16)0.f, ph_2 = (f16)0.f, ph_3 = (f16)0.f;
  f16 ph_4 = (f16)0.f, ph_5 = (f16)0.f, ph_6 = (f16)0.f, ph_7 = (f16)0.f;
  f16 vj0_0 = (f16)0.f, vj1_0 = (f16)0.f, vj2_0 = (f16)0.f;
  f16 vj0_1 = (f16)0.f, vj1_1 = (f16)0.f, vj2_1 = (f16)0.f;
  f16 vj0_2 = (f16)0.f, vj1_2 = (f16)0.f, vj2_2 = (f16)0.f;
  f16 vj0_3 = (f16)0.f, vj1_3 = (f16)0.f, vj2_3 = (f16)0.f;
  f16 vj0_4 = (f16)0.f, vj1_4 = (f16)0.f, vj2_4 = (f16)0.f;
  f16 vj0_5 = (f16)0.f, vj1_5 = (f16)0.f, vj2_5 = (f16)0.f;
  f16 vj0_6 = (f16)0.f, vj1_6 = (f16)0.f, vj2_6 = (f16)0.f;
  f16 vj0_7 = (f16)0.f, vj1_7 = (f16)0.f, vj2_7 = (f16)0.f;

#define MK_LOAD(S, RR) do { int rv_ = (RR); if (rv_ < cnt) {                  \
    int jj_ = ijL[rv_].y;                                                      \
    ph_##S = phi_h[(size_t)jj_ * 384 + t];                                     \
    if (g == 0) { const f16* vp_ = vh + (size_t)jj_ * 384 + f;                 \
      vj0_##S = vp_[0]; vj1_##S = vp_[128]; vj2_##S = vp_[256]; }              \
  } } while (0)

#define MK_PROC(S, RR) do { int rv_ = (RR); if (rv_ < cnt) {                   \
    int ix_ = ijL[rv_].x;                                                      \
    if (ix_ != prev_i) {                                                       \
      if (prev_i >= 0) {                                                       \
        if (g == 1) atomicAdd(s + (size_t)prev_i * 128 + f, a0);               \
        else { float* vb_ = v + (size_t)prev_i * 384 + f;                      \
          atomicAdd(vb_, a0); atomicAdd(vb_ + 128, a1); atomicAdd(vb_ + 256, a2); } \
        a0 = a1 = a2 = 0.f; }                                                  \
      prev_i = ix_; }                                                          \
    float ws_ = (float)wsT[t][rv_];                                            \
    float inv_ = (float)ph_##S * ws_;                                          \
    if (g == 0) { a0 = fmaf(inv_, (float)vj0_##S, a0);                         \
                  a1 = fmaf(inv_, (float)vj1_##S, a1);                         \
                  a2 = fmaf(inv_, (float)vj2_##S, a2); }                       \
    else if (g == 1) { a0 += inv_; }                                           \
    else { a0 = fmaf(inv_, unitL[3 * rv_ + 0], a0);                            \
           a1 = fmaf(inv_, unitL[3 * rv_ + 1], a1);                            \
           a2 = fmaf(inv_, unitL[3 * rv_ + 2], a2); }                          \
  } } while (0)

  MK_LOAD(0, 0); MK_LOAD(1, 1); MK_LOAD(2, 2); MK_LOAD(3, 3);
  MK_LOAD(4, 4); MK_LOAD(5, 5); MK_LOAD(6, 6); MK_LOAD(7, 7);
#pragma unroll
  for (int r = 0; r < (FULL ? MEPB : 1) * (FULL ? 1 : 1) && false; ++r) {}  // (no-op; keep structure clear)
  if (FULL) {
#pragma unroll
    for (int r = 0; r < MEPB; r += 8) {
      MK_PROC(0, r);     MK_LOAD(0, r + 8);
      MK_PROC(1, r + 1); MK_LOAD(1, r + 9);
      MK_PROC(2, r + 2); MK_LOAD(2, r + 10);
      MK_PROC(3, r + 3); MK_LOAD(3, r + 11);
      MK_PROC(4, r + 4); MK_LOAD(4, r + 12);
      MK_PROC(5, r + 5); MK_LOAD(5, r + 13);
      MK_PROC(6, r + 6); MK_LOAD(6, r + 14);
      MK_PROC(7, r + 7); MK_LOAD(7, r + 15);
    }
  } else {
    for (int r = 0; r < cnt; r += 8) {
      MK_PROC(0, r);     MK_LOAD(0, r + 8);
      MK_PROC(1, r + 1); MK_LOAD(1, r + 9);
      MK_PROC(2, r + 2); MK_LOAD(2, r + 10);
      MK_PROC(3, r + 3); MK_LOAD(3, r + 11);
      MK_PROC(4, r + 4); MK_LOAD(4, r + 12);
      MK_PROC(5, r + 5); MK_LOAD(5, r + 13);
      MK_PROC(6, r + 6); MK_LOAD(6, r + 14);
      MK_PROC(7, r + 7); MK_LOAD(7, r + 15);
    }
  }
#undef MK_LOAD
#undef MK_PROC
  // ---- final flush ----
  if (prev_i >= 0) {
    if (g == 1) {
      atomicAdd(s + (size_t)prev_i * 128 + f, a0);
    } else {
      float* vb = v + (size_t)prev_i * 384 + f;
      atomicAdd(vb, a0);
      atomicAdd(vb + 128, a1);
      atomicAdd(vb + 256, a2);
    }
  }
}

// ---------------- s_stack = [s, ||v_v||] (f16 out) ----------------
__global__ __launch_bounds__(256) void stack_kernel(
    const float* __restrict__ s, const float* __restrict__ v_v,
    f16* __restrict__ s_stack, int N)
{
  int idx = blockIdx.x * 256 + threadIdx.x;
  if (idx >= N * 128) return;
  int n = idx >> 7, g = idx & 127;
  float a = v_v[(size_t)n * 384 + g];
  float b = v_v[(size_t)n * 384 + 128 + g];
  float c = v_v[(size_t)n * 384 + 256 + g];
  s_stack[(size_t)n * 256 + g] = (f16)s[idx];
  s_stack[(size_t)n * 256 + 128 + g] = (f16)sqrtf(a * a + b * b + c * c + EPS_F);
}

// ---------------- gated update of s, v (+ f16 mirrors for next-layer reads) ----------------
__global__ __launch_bounds__(256) void apply_kernel(
    float* __restrict__ s, f16* __restrict__ s_h,
    float* __restrict__ v, f16* __restrict__ v_h,
    const float* __restrict__ u_v, const float* __restrict__ v_v,
    const float* __restrict__ sp, int N)
{
  int idx = blockIdx.x * 256 + threadIdx.x;
  if (idx >= N * 128) return;
  int n = idx >> 7, g = idx & 127;
  float sp0 = sp[(size_t)n * 384 + g];
  float sp1 = sp[(size_t)n * 384 + 128 + g];
  float sp2 = sp[(size_t)n * 384 + 256 + g];
  float dot = 0.f;
#pragma unroll
  for (int c = 0; c < 3; ++c) {
    size_t o = (size_t)n * 384 + c * 128 + g;
    float uv = u_v[o];
    float vn = fmaf(uv, sp0, v[o]);
    v[o] = vn;
    v_h[o] = (f16)vn;
    dot = fmaf(uv, v_v[o], dot);
  }
  float sn = s[idx] + dot * sp1 + sp2;
  s[idx] = sn;
  s_h[idx] = (f16)sn;
}

// ---------------- fused f16 MFMA readout (unsorted edges; register-prefetched gathers) ----------------
__global__ __launch_bounds__(256) void readout_gemm_kernel(
    const int* __restrict__ nbr, const float* __restrict__ xyz,
    const f16* __restrict__ s_h, const f16* __restrict__ w1t,
    const float* __restrict__ b1, const float* __restrict__ w2,
    const float* __restrict__ b2, float* __restrict__ out, int E)
{
  __shared__ f16 As[64][40];
  __shared__ f16 Bs[64][40];
  __shared__ float red[2][64];
  __shared__ int ijc[64][2];
  int t = threadIdx.x;
  int wave = t >> 6, lane = t & 63;
  int rw = wave & 1, cw = wave >> 1;
  int lr = lane & 15, quad = lane >> 4;
  int e0b = blockIdx.x * 64;
  if (t < 64) {
    int e = e0b + t;
    if (e < E) { ijc[t][0] = nbr[2 * e]; ijc[t][1] = nbr[2 * e + 1]; }
    else { ijc[t][0] = 0; ijc[t][1] = 0; }
  }
  __syncthreads();
  int m = t >> 2;             // one row (edge) per thread
  int c8 = (t & 3) * 8;       // 8 features within 32-k window
  int im = ijc[m][0], jm = ijc[m][1];
  bool okm = (e0b + m) < E;
  // prefetch all 8 row-segments (4 windows x i/j) - independent loads in flight
  f16x8 xa[4], ya[4];
  if (okm) {
#pragma unroll
    for (int w = 0; w < 4; ++w) {
      xa[w] = *(const f16x8*)(s_h + (size_t)im * 128 + w * 32 + c8);
      ya[w] = *(const f16x8*)(s_h + (size_t)jm * 128 + w * 32 + c8);
    }
  } else {
#pragma unroll
    for (int w = 0; w < 4; ++w)
      for (int q = 0; q < 8; ++q) { xa[w][q] = (f16)0.0f; ya[w][q] = (f16)0.0f; }
  }
  floatx4 acc[2][2] = {};
#pragma unroll
  for (int w = 0; w < 4; ++w) {
    *(f16x8*)&As[m][c8] = xa[w] + ya[w];
    {
      int sm = t >> 2, sk = (t & 3) * 8;
      *(f16x8*)&Bs[sm][sk] = *(const f16x8*)(w1t + (size_t)sm * 128 + w * 32 + sk);
    }
    __syncthreads();
    f16x8 af[2], bfr[2];
#pragma unroll
    for (int tr = 0; tr < 2; ++tr)
      af[tr] = *(const f16x8*)&As[rw * 32 + tr * 16 + lr][quad * 8];
#pragma unroll
    for (int tc = 0; tc < 2; ++tc)
      bfr[tc] = *(const f16x8*)&Bs[cw * 32 + tc * 16 + lr][quad * 8];
#pragma unroll
    for (int tr = 0; tr < 2; ++tr)
#pragma unroll
      for (int tc = 0; tc < 2; ++tc)
        acc[tr][tc] = __builtin_amdgcn_mfma_f32_16x16x32_f16(af[tr], bfr[tc], acc[tr][tc], 0, 0, 0);
    __syncthreads();
  }
  float b1v[2], w2v[2];
#pragma unroll
  for (int tc = 0; tc < 2; ++tc) {
    int col = cw * 32 + tc * 16 + lr;
    b1v[tc] = b1[col];
    w2v[tc] = w2[col];
  }
#pragma unroll
  for (int tr = 0; tr < 2; ++tr) {
#pragma unroll
    for (int r = 0; r < 4; ++r) {
      float p = 0.f;
#pragma unroll
      for (int tc = 0; tc < 2; ++tc)
        p += silu_f(acc[tr][tc][r] + b1v[tc]) * w2v[tc];
#pragma unroll
      for (int ofs = 1; ofs < 16; ofs <<= 1) p += __shfl_xor(p, ofs, 64);
      if (lr == 0) red[cw][rw * 32 + tr * 16 + quad * 4 + r] = p;
    }
  }
  __syncthreads();
  if (t < 64) {
    int e = e0b + t;
    if (e < E) {
      float fs = red[0][t] + red[1][t] + b2[0];
      int i = ijc[t][0], j = ijc[t][1];
      float dx = xyz[3 * i + 0] - xyz[3 * j + 0];
      float dy = xyz[3 * i + 1] - xyz[3 * j + 1];
      float dz = xyz[3 * i + 2] - xyz[3 * j + 2];
      float dis = sqrtf(dx * dx + dy * dy + dz * dz);  // no EPS here (matches ref)
      float sc = fs / dis;
      float fx = sc * dx, fy = sc * dy, fz = sc * dz;
      atomicAdd(out + (size_t)i * 3 + 0, fx);
      atomicAdd(out + (size_t)i * 3 + 1, fy);
      atomicAdd(out + (size_t)i * 3 + 2, fz);
      atomicAdd(out + (size_t)j * 3 + 0, -fx);
      atomicAdd(out + (size_t)j * 3 + 1, -fy);
      atomicAdd(out + (size_t)j * 3 + 2, -fz);
    }
  }
}

extern "C" void kernel_launch(void* const* d_in, const int* in_sizes, int n_in,
                              void* d_out, int out_size, void* d_ws, size_t ws_size,
                              hipStream_t stream) {
  const float* xyz    = (const float*)d_in[0];
  const int*   z      = (const int*)d_in[1];
  const int*   nbr    = (const int*)d_in[2];
  const float* embed  = (const float*)d_in[3];
  const float* msg_w1 = (const float*)d_in[4];
  const float* msg_b1 = (const float*)d_in[5];
  const float* msg_w2 = (const float*)d_in[6];
  const float* msg_b2 = (const float*)d_in[7];
  const float* dist_w = (const float*)d_in[8];
  const float* dist_b = (const float*)d_in[9];
  const float* upd_u  = (const float*)d_in[10];
  const float* upd_v  = (const float*)d_in[11];
  const float* upd_w1 = (const float*)d_in[12];
  const float* upd_b1 = (const float*)d_in[13];
  const float* upd_w2 = (const float*)d_in[14];
  const float* upd_b2 = (const float*)d_in[15];
  const float* ero_w1 = (const float*)d_in[16];
  const float* ero_b1 = (const float*)d_in[17];
  const float* ero_w2 = (const float*)d_in[18];
  const float* ero_b2 = (const float*)d_in[19];

  const int N = in_sizes[1];      // 10000
  const int E = in_sizes[2] / 2;  // 160000
  const int L = 3;

  char* ws = (char*)d_ws;
  size_t off = 0;
  auto alloc = [&](size_t bytes) -> void* {
    void* p = ws + off;
    off += (bytes + 255) & ~(size_t)255;
    return p;
  };
  float* unit_s = (float*)alloc((size_t)E * 3 * 4);
  f16*   rbf_h  = (f16*)alloc((size_t)E * 32 * 2);
  int2*  ij_s   = (int2*)alloc((size_t)E * 8);
  int*   order  = (int*)alloc((size_t)E * 4);
  float* s      = (float*)alloc((size_t)N * 128 * 4);
  f16*   s_h    = (f16*)alloc((size_t)N * 128 * 2);
  float* vA     = (float*)alloc((size_t)N * 384 * 4);
  f16*   vhA    = (f16*)alloc((size_t)N * 384 * 2);
  f16*   phi_h  = (f16*)alloc((size_t)N * 384 * 2);
  f16*   w1t    = (f16*)alloc((size_t)64 * 128 * 2);
  f16*   dwf    = (f16*)alloc((size_t)3 * 24 * 64 * 8 * 2);
  int*   histx  = (int*)alloc((size_t)(N + 1) * 4);
  int*   startp = (int*)alloc((size_t)(N + 1) * 4);
  int*   cursor = (int*)alloc((size_t)N * 4);
  float* u_v    = (float*)alloc((size_t)N * 384 * 4);
  float* v_v    = (float*)alloc((size_t)N * 384 * 4);
  float* sp     = (float*)alloc((size_t)N * 384 * 4);
  f16*   sstk_h = (f16*)alloc((size_t)N * 256 * 2);
  f16*   h_h    = (f16*)alloc((size_t)N * 128 * 2);

  auto cdiv = [](int a, int b) { return (a + b - 1) / b; };

  // ---- setup: deterministic CSR + weight pre-pack ----
  hipMemsetAsync(vA, 0, (size_t)N * 384 * 4, stream);
  hipMemsetAsync(vhA, 0, (size_t)N * 384 * 2, stream);
  hipMemsetAsync(histx, 0, (size_t)(N + 1) * 4, stream);
  hist_kernel<<<cdiv(E, 256), 256, 0, stream>>>(nbr, histx, E);
  scan_kernel<<<1, 1024, 0, stream>>>(histx, startp, cursor, N);
  scatter_id_kernel<<<cdiv(E, 256), 256, 0, stream>>>(nbr, cursor, order, E);
  segsort_kernel<<<cdiv(N, 4), 256, 0, stream>>>(order, startp, N);
  geom_fill_kernel<<<cdiv(E, 256), 256, 0, stream>>>(
      order, nbr, xyz, ij_s, unit_s, rbf_h, E);
  embed_kernel<<<cdiv(N * 128, 256), 256, 0, stream>>>(z, embed, s, s_h, N);
  w1t_kernel<<<cdiv(64 * 128, 256), 256, 0, stream>>>(ero_w1, w1t);
  dwfrag_kernel<<<cdiv(3 * 24 * 64 * 8, 256), 256, 0, stream>>>(dist_w, dist_b, dwf);

  int full_blocks = E / MEPB;
  int tail = E - full_blocks * MEPB;

  for (int l = 0; l < L; ++l) {
    // phi = silu(s @ msg_w1 + b1) @ msg_w2 + b2  -> f16 (A read from f16 mirror)
    gemm_kernel<true, 1, true><<<dim3(cdiv(N, 64), 2), 256, 0, stream>>>(
        s_h, msg_w1 + (size_t)l * 128 * 128, msg_b1 + (size_t)l * 128, nullptr, h_h, N, 128, 128);
    gemm_kernel<false, 1, true><<<dim3(cdiv(N, 64), 6), 256, 0, stream>>>(
        h_h, msg_w2 + (size_t)l * 128 * 384, msg_b2 + (size_t)l * 384, nullptr, phi_h, N, 384, 128);
    // MFMA-ws message; atomic flush into s / v (in place)
    if (full_blocks)
      message_kernel<true><<<full_blocks, 384, 0, stream>>>(
          ij_s, unit_s, rbf_h, dwf + (size_t)l * 24 * 64 * 8,
          phi_h, vhA, s, vA, E, 0);
    if (tail)
      message_kernel<false><<<1, 384, 0, stream>>>(
          ij_s, unit_s, rbf_h, dwf + (size_t)l * 24 * 64 * 8,
          phi_h, vhA, s, vA, E, full_blocks * MEPB);
    // update block
    gemm_dual_kernel<<<dim3(cdiv(N * 3, 64), 2), 256, 0, stream>>>(
        vA, upd_u + (size_t)l * 128 * 128, upd_v + (size_t)l * 128 * 128,
        u_v, v_v, N * 3, 128, 128);
    stack_kernel<<<cdiv(N * 128, 256), 256, 0, stream>>>(s, v_v, sstk_h, N);
    gemm_kernel<true, 1, true><<<dim3(cdiv(N, 64), 2), 256, 0, stream>>>(
        sstk_h, upd_w1 + (size_t)l * 256 * 128, upd_b1 + (size_t)l * 128, nullptr, h_h, N, 128, 256);
    gemm_kernel<false, 0, true><<<dim3(cdiv(N, 64), 6), 256, 0, stream>>>(
        h_h, upd_w2 + (size_t)l * 128 * 384, upd_b2 + (size_t)l * 384, nullptr, sp, N, 384, 128);
    apply_kernel<<<cdiv(N * 128, 256), 256, 0, stream>>>(
        s, s_h, vA, vhA, u_v, v_v, sp, N);
  }

  // fused f16 MFMA readout (unsorted edges, register-prefetched gathers)
  hipMemsetAsync(d_out, 0, (size_t)out_size * 4, stream);
  readout_gemm_kernel<<<cdiv(E, 64), 256, 0, stream>>>(
      nbr, xyz, s_h, w1t, ero_b1, ero_w2, ero_b2, (float*)d_out, E);
}